// Round 6
// baseline (955.874 us; speedup 1.0000x reference)
//
#include <hip/hip_runtime.h>
#include <math.h>

// ---------------------------------------------------------------------------
// Round 15: software-pipeline the persistent LSTM's weight streaming.
// r14 post-mortem: structure is right (FETCH 24 MB, zero sync) but the chain
// is L2-LATENCY-bound (MfmaUtil 9%, VALU 20%, HBM 1%): each kk's 12
// B-fragments are loaded from L2 (~250 cyc) with dependent MFMAs right
// behind, 1 block/CU -> nothing hides the round trip. Fix: manual register
// double-buffer bA/bB over kk, written as 7 static even/odd pairs (all
// indices compile-time, no dynamic-indexed locals). Loads for kk+1 issue
// before MFMAs of kk. Floors: MFMA 76us, L2-BW 143us -> target ~250us.
// ---------------------------------------------------------------------------

using bf16x8 = __attribute__((ext_vector_type(8))) short;
using f32x4  = __attribute__((ext_vector_type(4))) float;

enum { EPI_NONE = 0, EPI_RELU = 1, EPI_TANH = 2 };

__device__ inline unsigned short f2bf(float f) {
    union { float f; unsigned u; } v; v.f = f;
    unsigned r = v.u + 0x7FFFu + ((v.u >> 16) & 1u);
    return (unsigned short)(r >> 16);
}
__device__ inline float sigf(float x) {
    return __fdividef(1.f, 1.f + __expf(-x));
}
__device__ inline float tanhfast(float x) {
    return 1.f - __fdividef(2.f, 1.f + __expf(2.f * x));
}

__device__ inline void gll16(const void* g, void* l) {
    __builtin_amdgcn_global_load_lds(
        (const __attribute__((address_space(1))) unsigned int*)(uintptr_t)g,
        (__attribute__((address_space(3))) unsigned int*)(unsigned int)(uintptr_t)l,
        16, 0, 0);
}

// ---------------------------------------------------------------------------
// Persistent LSTM: grid 256 x 512 threads. Block b owns batch rows
// [32b, 32b+32). A-buffer [32][456] bf16 in LDS. Wave w owns packed gate
// cols [192w, 192w+192) = units {48w..48w+47}.
// Packed col layout (from pack_lstm2): n' = (u>>4)*64 + g*16 + (u&15).
// ---------------------------------------------------------------------------
#define PROWS 32
#define PLDA  456

// load the 12 B-fragments for K-slice kkv into named regs dst[0..11]
#define LOADB(dst, kkv)                                                        \
    _Pragma("unroll")                                                          \
    for (int ni = 0; ni < 12; ++ni)                                            \
        dst[ni] = *(const bf16x8*)(wbase + (size_t)ni * 16 * 448 + (kkv) * 32);

// load the 2 A-fragments for K-slice kkv
#define LOADA(dst, kkv)                                                        \
    _Pragma("unroll")                                                          \
    for (int mi = 0; mi < 2; ++mi)                                             \
        dst[mi] = *(const bf16x8*)&Ab[(mi * 16 + lm) * PLDA + (kkv) * 32       \
                                      + quad * 8];

// 24 MFMAs: acc += aF x bW
#define MFMA12(aF, bW)                                                         \
    _Pragma("unroll")                                                          \
    for (int ni = 0; ni < 12; ++ni) {                                          \
        acc[0][ni] = __builtin_amdgcn_mfma_f32_16x16x32_bf16(                  \
            aF[0], bW[ni], acc[0][ni], 0, 0, 0);                               \
        acc[1][ni] = __builtin_amdgcn_mfma_f32_16x16x32_bf16(                  \
            aF[1], bW[ni], acc[1][ni], 0, 0, 0);                               \
    }

__global__ __launch_bounds__(512, 2)
void lstm_persist(const float* __restrict__ x,
                  const float* __restrict__ m,
                  const unsigned short* __restrict__ WtE,
                  const unsigned short* __restrict__ WtD,
                  const float* __restrict__ bIE,
                  const float* __restrict__ bID,
                  unsigned short* __restrict__ dcd)
{
    __shared__ __attribute__((aligned(16))) unsigned short Ab[PROWS * PLDA];
    const int tid  = threadIdx.x;
    const int lane = tid & 63;
    const int w    = tid >> 6;           // 0..7
    const int lm   = lane & 15, quad = lane >> 4;
    const int brow = blockIdx.x * PROWS;

    // zero A-buffer (pads stay 0 forever), then stage x slice t=0
    for (int i = tid; i < PROWS * PLDA; i += 512) Ab[i] = 0;
    __syncthreads();
    for (int i = tid; i < PROWS * 69; i += 512) {
        const int r = i / 69, f = i - r * 69;
        Ab[r * PLDA + f] = f2bf(x[((size_t)(brow + r) * 7 + 0) * 69 + f]);
    }

    float creg[2][3][4] = {};   // cell state: [mi][a][r] for unit (3w+a)*16+lm
    float bI[3][4];             // bias: [a][gate]

    for (int s = 0; s < 14; ++s) {
        const bool enc = (s < 7);
        const int t = enc ? s : s - 7;
        const unsigned short* Wt = enc ? WtE : WtD;
        const unsigned short* wbase =
            Wt + (size_t)(w * 192 + lm) * 448 + quad * 8;

        if (s == 0 || s == 7) {
            const float* bsrc = enc ? bIE : bID;
            #pragma unroll
            for (int a = 0; a < 3; ++a)
                #pragma unroll
                for (int g = 0; g < 4; ++g)
                    bI[a][g] = bsrc[(3 * w + a) * 64 + g * 16 + lm];
        }

        __syncthreads();   // Ab (x for s, h from s-1) fully written

        f32x4 acc[2][12] = {};
        // software-pipelined kk loop: 7 static even/odd pairs, B double-
        // buffered in registers (bA/bB), loads lead MFMAs by one slice.
        {
            bf16x8 bA[12], bB[12], aF0[2], aF1[2];
            LOADB(bA, 0)
            LOADA(aF0, 0)
            #pragma unroll 1
            for (int kk2 = 0; kk2 < 7; ++kk2) {
                const int kk = kk2 * 2;
                LOADB(bB, kk + 1)      // prefetch odd slice
                LOADA(aF1, kk + 1)
                MFMA12(aF0, bA)        // compute even slice
                if (kk2 < 6) {
                    LOADB(bA, kk + 2)  // prefetch next even slice
                    LOADA(aF0, kk + 2)
                }
                MFMA12(aF1, bB)        // compute odd slice
            }
        }

        __syncthreads();   // all Ab reads done before h overwrite

        // epilogue: gates -> c (regs) -> h -> Ab[hoff+u] (+ dcd in dec phase)
        const int hoff = (s < 6) ? 69 : 45;   // layout of step s+1
        #pragma unroll
        for (int mi = 0; mi < 2; ++mi)
            #pragma unroll
            for (int a = 0; a < 3; ++a) {
                const int u = (3 * w + a) * 16 + lm;
                const bool uok = (u < 356);
                #pragma unroll
                for (int r = 0; r < 4; ++r) {
                    const float zi = acc[mi][a * 4 + 0][r] + bI[a][0];
                    const float zf = acc[mi][a * 4 + 1][r] + bI[a][1];
                    const float zg = acc[mi][a * 4 + 2][r] + bI[a][2];
                    const float zo = acc[mi][a * 4 + 3][r] + bI[a][3];
                    const float cn = sigf(zf) * creg[mi][a][r]
                                   + sigf(zi) * tanhfast(zg);
                    creg[mi][a][r] = cn;
                    const unsigned short hb = f2bf(sigf(zo) * tanhfast(cn));
                    const int rl = mi * 16 + quad * 4 + r;
                    if (uok) {
                        if (s < 13) Ab[rl * PLDA + hoff + u] = hb;
                        if (!enc)
                            dcd[(size_t)(brow + rl) * 2496 + t * 356 + u] = hb;
                    }
                }
            }

        // stage x/m slice for step s+1 (disjoint from h region)
        const int sn = s + 1;
        if (sn < 7) {
            for (int i = tid; i < PROWS * 69; i += 512) {
                const int r = i / 69, f = i - r * 69;
                Ab[r * PLDA + f] =
                    f2bf(x[((size_t)(brow + r) * 7 + sn) * 69 + f]);
            }
        } else if (sn < 14) {
            for (int i = tid; i < PROWS * 45; i += 512) {
                const int r = i / 45, f = i - r * 45;
                Ab[r * PLDA + f] =
                    f2bf(m[((size_t)(brow + r) * 7 + (sn - 7)) * 45 + f]);
            }
        }
    }
}

// ---- MLP GEMM machinery (unchanged, proven) ----

#define STAGE(A_, Bt_, K_, k0_, b_)                                            \
    {                                                                          \
        const int row = tid >> 2, kc = tid & 3;                                \
        gll16((A_)  + (size_t)(m0 + row) * (K_) + (k0_) + kc * 8,              \
              (void*)&As[b_][tid * 8]);                                        \
        gll16((Bt_) + (size_t)(n0 + row) * (K_) + (k0_) + kc * 8,              \
              (void*)&Bs[b_][tid * 8]);                                        \
    }

#define GEMM_CORE(A_, Bt_, K_)                                                 \
    STAGE(A_, Bt_, K_, 0, 0)                                                   \
    {                                                                          \
        const int niter = (K_) / 32;                                           \
        for (int it = 0; it < niter; ++it) {                                   \
            __syncthreads();                                                   \
            if (it + 1 < niter) {                                              \
                const int kn = (it + 1) * 32, bn = (it + 1) & 1;               \
                STAGE(A_, Bt_, K_, kn, bn)                                     \
            }                                                                  \
            const unsigned short* Asb = As[it & 1];                            \
            const unsigned short* Bsb = Bs[it & 1];                            \
            bf16x8 aF[2], bF[4];                                               \
            _Pragma("unroll")                                                  \
            for (int mi = 0; mi < 2; ++mi)                                     \
                aF[mi] = *(const bf16x8*)(Asb + (wr*32 + mi*16 + lm)*32 + quad*8);\
            _Pragma("unroll")                                                  \
            for (int ni = 0; ni < 4; ++ni)                                     \
                bF[ni] = *(const bf16x8*)(Bsb + (wc*64 + ni*16 + lm)*32 + quad*8);\
            _Pragma("unroll")                                                  \
            for (int mi = 0; mi < 2; ++mi)                                     \
                _Pragma("unroll")                                              \
                for (int ni = 0; ni < 4; ++ni)                                 \
                    acc[mi][ni] = __builtin_amdgcn_mfma_f32_16x16x32_bf16(     \
                        aF[mi], bF[ni], acc[mi][ni], 0, 0, 0);                 \
        }                                                                      \
    }

#define GEMM_PREAMBLE                                                          \
    __shared__ __attribute__((aligned(16))) unsigned short As[2][128 * 32];    \
    __shared__ __attribute__((aligned(16))) unsigned short Bs[2][128 * 32];    \
    const int tid  = threadIdx.x;                                              \
    const int lane = tid & 63;                                                 \
    const int w    = tid >> 6;          /* 0..7 */                             \
    const int wr   = w >> 1, wc = w & 1; /* 4x2 wave grid */                   \
    const int lm   = lane & 15, quad = lane >> 4;                              \
    const int m0   = blockIdx.x * 128, n0 = blockIdx.y * 128;                  \
    f32x4 acc[2][4] = {};

template <int EPI, int OUT_BF16, int NGUARD>
__global__ __launch_bounds__(512, 6)
void gemm_mfma(const unsigned short* __restrict__ A,
               const unsigned short* __restrict__ Bt,
               const float* __restrict__ bias,
               void* __restrict__ Cv, int ldc, int Nreal, int K)
{
    GEMM_PREAMBLE
    GEMM_CORE(A, Bt, K)
    #pragma unroll
    for (int mi = 0; mi < 2; ++mi)
        #pragma unroll
        for (int r = 0; r < 4; ++r) {
            const size_t row = m0 + wr * 32 + mi * 16 + quad * 4 + r;
            #pragma unroll
            for (int ni = 0; ni < 4; ++ni) {
                const int col = n0 + wc * 64 + ni * 16 + lm;
                if (!NGUARD || col < Nreal) {
                    float v = acc[mi][ni][r] + bias[col];
                    if (EPI == EPI_RELU) v = fmaxf(v, 0.f);
                    if (EPI == EPI_TANH) v = tanhfast(v);
                    if (OUT_BF16) ((unsigned short*)Cv)[row * ldc + col] = f2bf(v);
                    else          ((float*)Cv)[row * ldc + col] = v;
                }
            }
        }
}

// ---- LSTM weight pack (enc+dec in one launch; blockIdx.y selects) ----
// dec packed to Kp=448 (zeros k>=401) so persist kernel uses K=448 always.
struct PackArgs {
    const float *Wa0, *Wb0, *bias0; unsigned short* Wt0; float* bI0; int K10, K0, Kp0;
    const float *Wa1, *Wb1, *bias1; unsigned short* Wt1; float* bI1; int K11, K1, Kp1;
};
__global__ void pack_lstm2(PackArgs p)
{
    const float* Wa  = blockIdx.y ? p.Wa1  : p.Wa0;
    const float* Wb  = blockIdx.y ? p.Wb1  : p.Wb0;
    const float* bias= blockIdx.y ? p.bias1: p.bias0;
    unsigned short* Wt = blockIdx.y ? p.Wt1 : p.Wt0;
    float* biasI = blockIdx.y ? p.bI1 : p.bI0;
    const int K1 = blockIdx.y ? p.K11 : p.K10;
    const int K  = blockIdx.y ? p.K1  : p.K0;
    const int Kp = blockIdx.y ? p.Kp1 : p.Kp0;
    const int idx = blockIdx.x * 256 + threadIdx.x;
    if (idx >= 1536 * Kp) return;
    const int np = idx / Kp, k = idx - np * Kp;
    const int ub = np >> 6, g = (np >> 4) & 3, ul = np & 15;
    const int u = ub * 16 + ul;
    const bool valid = (u < 356);
    const int norig = g * 356 + u;
    float v = 0.f;
    if (valid && k < K)
        v = (k < K1) ? Wa[(size_t)k * 1424 + norig]
                     : Wb[(size_t)(k - K1) * 1424 + norig];
    Wt[(size_t)np * Kp + k] = f2bf(v);
    if (k == 0) biasI[np] = valid ? bias[norig] : 0.f;
}

// ---- MLP weight transpose+pack (fp32 [K][N] -> bf16 [Np][Kp]) ----
__global__ void transpose_pack(const float* __restrict__ W, int K, int N,
                               unsigned short* __restrict__ Wt, int Kp, int Np)
{
    __shared__ float t[32][33];
    const int n0 = blockIdx.x * 32, k0 = blockIdx.y * 32;
    const int tx = threadIdx.x, ty = threadIdx.y;
    #pragma unroll
    for (int r = 0; r < 4; ++r) {
        const int k = k0 + ty + 8 * r, n = n0 + tx;
        t[ty + 8 * r][tx] = (k < K && n < N) ? W[(size_t)k * N + n] : 0.f;
    }
    __syncthreads();
    #pragma unroll
    for (int r = 0; r < 4; ++r) {
        const int k = k0 + tx, n = n0 + ty + 8 * r;
        if (k < Kp && n < Np) Wt[(size_t)n * Kp + k] = f2bf(t[tx][ty + 8 * r]);
    }
}

// three 1024x1024 transposes in one launch (blockIdx.z selects)
struct WP3 { const float *s0, *s1, *s2; unsigned short *d0, *d1, *d2; };
__global__ void transpose_pack3(WP3 p)
{
    __shared__ float t[32][33];
    const float* W = (blockIdx.z == 0) ? p.s0 : (blockIdx.z == 1) ? p.s1 : p.s2;
    unsigned short* Wt = (blockIdx.z == 0) ? p.d0 : (blockIdx.z == 1) ? p.d1 : p.d2;
    const int n0 = blockIdx.x * 32, k0 = blockIdx.y * 32;
    const int tx = threadIdx.x, ty = threadIdx.y;
    #pragma unroll
    for (int r = 0; r < 4; ++r)
        t[ty + 8 * r][tx] = W[(size_t)(k0 + ty + 8 * r) * 1024 + n0 + tx];
    __syncthreads();
    #pragma unroll
    for (int r = 0; r < 4; ++r)
        Wt[(size_t)(n0 + ty + 8 * r) * 1024 + k0 + tx] = f2bf(t[tx][ty + 8 * r]);
}

// ---- zero dcd pad cols (2492..2495 of each row) ----
__global__ void zero_dcd_pad(unsigned short* __restrict__ dcd)
{
    const int i = blockIdx.x * 256 + threadIdx.x;
    if (i < 8192 * 4) dcd[(size_t)(i >> 2) * 2496 + 2492 + (i & 3)] = 0;
}

extern "C" void kernel_launch(void* const* d_in, const int* in_sizes, int n_in,
                              void* d_out, int out_size, void* d_ws, size_t ws_size,
                              hipStream_t stream)
{
    const float* x     = (const float*)d_in[0];
    const float* m     = (const float*)d_in[1];
    const float* enc_W = (const float*)d_in[2];
    const float* enc_U = (const float*)d_in[3];
    const float* enc_b = (const float*)d_in[4];
    const float* dec_W = (const float*)d_in[5];
    const float* dec_Um= (const float*)d_in[6];
    const float* dec_b = (const float*)d_in[7];
    const float* W_map = (const float*)d_in[8];
    const float* b_map = (const float*)d_in[9];
    const float* W1    = (const float*)d_in[10];
    const float* b1    = (const float*)d_in[11];
    const float* W2    = (const float*)d_in[12];
    const float* b2    = (const float*)d_in[13];
    const float* W3    = (const float*)d_in[14];
    const float* b3    = (const float*)d_in[15];
    const float* W_out = (const float*)d_in[16];
    const float* b_out = (const float*)d_in[17];
    float* out = (float*)d_out;

    const int B = 8192, FE = 69, FD = 45;
    const int KMP = 2496;

    char* ws = (char*)d_ws;
    size_t off = 0;
    auto alloc = [&](size_t bytes) -> void* {
        void* p = ws + off; off = (off + bytes + 255) & ~(size_t)255; return p;
    };
    unsigned short* WtE = (unsigned short*)alloc((size_t)1536 * 448 * 2);
    unsigned short* WtD = (unsigned short*)alloc((size_t)1536 * 448 * 2);
    unsigned short* WtM = (unsigned short*)alloc((size_t)1024 * KMP * 2);
    unsigned short* Wt1 = (unsigned short*)alloc((size_t)1024 * 1024 * 2);
    unsigned short* Wt2 = (unsigned short*)alloc((size_t)1024 * 1024 * 2);
    unsigned short* Wt3 = (unsigned short*)alloc((size_t)1024 * 1024 * 2);
    unsigned short* WtO = (unsigned short*)alloc((size_t)256 * 1024 * 2);
    float* bIE = (float*)alloc(1536 * 4);
    float* bID = (float*)alloc(1536 * 4);
    unsigned short* dcd = (unsigned short*)alloc((size_t)B * KMP * 2);
    unsigned short* a1  = (unsigned short*)alloc((size_t)B * 1024 * 2);
    unsigned short* a2  = (unsigned short*)alloc((size_t)B * 1024 * 2);

    // ---- weight packing (both LSTMs padded to Kp=448) ----
    PackArgs pa{enc_W, enc_U, enc_b, WtE, bIE, FE, FE + 356, 448,
                dec_W, dec_Um, dec_b, WtD, bID, FD, FD + 356, 448};
    pack_lstm2<<<dim3((1536 * 448 + 255) / 256, 2), 256, 0, stream>>>(pa);
    const dim3 tb(32, 8);
    transpose_pack<<<dim3(1024 / 32, KMP / 32), tb, 0, stream>>>(
        W_map, 2492, 1024, WtM, KMP, 1024);
    WP3 p3{W1, W2, W3, Wt1, Wt2, Wt3};
    transpose_pack3<<<dim3(32, 32, 3), tb, 0, stream>>>(p3);
    transpose_pack<<<dim3(256 / 32, 1024 / 32), tb, 0, stream>>>(
        W_out, 1024, 168, WtO, 1024, 256);
    zero_dcd_pad<<<(8192 * 4 + 255) / 256, 256, 0, stream>>>(dcd);

    // ---- persistent LSTM: one plain launch, zero barriers ----
    lstm_persist<<<256, 512, 0, stream>>>(x, m, WtE, WtD, bIE, bID, dcd);

    // ---- MLP head ----
    gemm_mfma<EPI_RELU, 1, 0><<<dim3(64, 8), 512, 0, stream>>>(
        dcd, WtM, b_map, a1, 1024, 1024, KMP);
    gemm_mfma<EPI_TANH, 1, 0><<<dim3(64, 8), 512, 0, stream>>>(
        a1, Wt1, b1, a2, 1024, 1024, 1024);
    gemm_mfma<EPI_TANH, 1, 0><<<dim3(64, 8), 512, 0, stream>>>(
        a2, Wt2, b2, a1, 1024, 1024, 1024);
    gemm_mfma<EPI_TANH, 1, 0><<<dim3(64, 8), 512, 0, stream>>>(
        a1, Wt3, b3, a2, 1024, 1024, 1024);
    gemm_mfma<EPI_NONE, 0, 1><<<dim3(64, 2), 512, 0, stream>>>(
        a2, WtO, b_out, out, 168, 168, 1024);
}

// Round 7
// 777.492 us; speedup vs baseline: 1.2294x; 1.2294x over previous
//
#include <hip/hip_runtime.h>
#include <math.h>

// ---------------------------------------------------------------------------
// Round 16: LDS-staged weight streaming for the persistent LSTM.
// r15 post-mortem: register double-buffer was DEFEATED by the compiler's
// 128-VGPR cap (needed ~210) -> loads serialized, MfmaUtil stuck at 9%.
// Fix: (a) repack weights so each wave's (kk,ni) fragment is 1KB contiguous;
// (b) stage each 32-K weight slice (96 KB, all cols) into LDS via
// global_load_lds (zero VGPR cost, fully coalesced), double-barrier per kk,
// stage of kk+1 issued before MFMAs of kk (T3-minimum pattern);
// (c) pin amdgpu_waves_per_eu(2,2) (LDS 124.5 KB forces 1 block/CU anyway).
// L2-BW floor ~10us/step -> chain target ~200-280us.
// ---------------------------------------------------------------------------

using bf16x8 = __attribute__((ext_vector_type(8))) short;
using f32x4  = __attribute__((ext_vector_type(4))) float;

enum { EPI_NONE = 0, EPI_RELU = 1, EPI_TANH = 2 };

__device__ inline unsigned short f2bf(float f) {
    union { float f; unsigned u; } v; v.f = f;
    unsigned r = v.u + 0x7FFFu + ((v.u >> 16) & 1u);
    return (unsigned short)(r >> 16);
}
__device__ inline float sigf(float x) {
    return __fdividef(1.f, 1.f + __expf(-x));
}
__device__ inline float tanhfast(float x) {
    return 1.f - __fdividef(2.f, 1.f + __expf(2.f * x));
}

__device__ inline void gll16(const void* g, void* l) {
    __builtin_amdgcn_global_load_lds(
        (const __attribute__((address_space(1))) unsigned int*)(uintptr_t)g,
        (__attribute__((address_space(3))) unsigned int*)(unsigned int)(uintptr_t)l,
        16, 0, 0);
}

// ---------------------------------------------------------------------------
// Persistent LSTM: grid 256 x 512 threads, 1 block/CU (LDS 124.5 KB).
// Block b owns batch rows [32b, 32b+32). Ab [32][456] bf16 holds x|h.
// Wave w owns packed gate cols [192w,192w+192) = units {48w..48w+47}.
// Weight layout (pack_lstm2): elem(np=w*192+ni*16+lm, k=kk*32+kq) stored at
//   ((w*14+kk)*12+ni)*512 + lm*32 + kq   -> each (w,kk,ni) fragment is 1KB
// contiguous; a kk-slice for wave w is 12KB contiguous (region stride 86016).
// Bs LDS mirrors it: Bs[(w*12+ni)*512 + lm*32 + kq], staged via gll16.
// ---------------------------------------------------------------------------
#define PROWS 32
#define PLDA  456

// stage the 96KB weight slice for K-chunk kkv into Bs (12 gll16/thread)
#define STAGEW(kkv)                                                            \
    _Pragma("unroll")                                                          \
    for (int r = 0; r < 12; ++r)                                               \
        gll16(Wt + (size_t)bOff[r] + (kkv) * 6144,                             \
              (void*)&Bs[(tid + r * 512) * 8]);

// load the 12 B-fragments of wave w from Bs (ds_read_b128 each)
#define LOADB_LDS(dst)                                                         \
    _Pragma("unroll")                                                          \
    for (int ni = 0; ni < 12; ++ni)                                            \
        dst[ni] = *(const bf16x8*)&Bs[(w * 12 + ni) * 512 + lm * 32            \
                                      + quad * 8];

// load the 2 A-fragments for K-slice kkv from Ab
#define LOADA(dst, kkv)                                                        \
    _Pragma("unroll")                                                          \
    for (int mi = 0; mi < 2; ++mi)                                             \
        dst[mi] = *(const bf16x8*)&Ab[(mi * 16 + lm) * PLDA + (kkv) * 32       \
                                      + quad * 8];

// 24 MFMAs: acc += aF x bW
#define MFMA12(aF, bW)                                                         \
    _Pragma("unroll")                                                          \
    for (int ni = 0; ni < 12; ++ni) {                                          \
        acc[0][ni] = __builtin_amdgcn_mfma_f32_16x16x32_bf16(                  \
            aF[0], bW[ni], acc[0][ni], 0, 0, 0);                               \
        acc[1][ni] = __builtin_amdgcn_mfma_f32_16x16x32_bf16(                  \
            aF[1], bW[ni], acc[1][ni], 0, 0, 0);                               \
    }

__global__ __attribute__((amdgpu_flat_work_group_size(512, 512),
                          amdgpu_waves_per_eu(2, 2)))
void lstm_persist(const float* __restrict__ x,
                  const float* __restrict__ m,
                  const unsigned short* __restrict__ WtE,
                  const unsigned short* __restrict__ WtD,
                  const float* __restrict__ bIE,
                  const float* __restrict__ bID,
                  unsigned short* __restrict__ dcd)
{
    __shared__ __attribute__((aligned(16))) unsigned short Ab[PROWS * PLDA];
    __shared__ __attribute__((aligned(16))) unsigned short Bs[49152];
    const int tid  = threadIdx.x;
    const int lane = tid & 63;
    const int w    = tid >> 6;           // 0..7
    const int lm   = lane & 15, quad = lane >> 4;
    const int brow = blockIdx.x * PROWS;

    // per-thread staging offsets (step/kk-invariant): chunk cc -> weight elem
    int bOff[12];
    #pragma unroll
    for (int r = 0; r < 12; ++r) {
        const int cc = tid + r * 512;          // 16B-chunk index, 0..6143
        const int wreg = cc / 768;             // weight w-region (768 chunks)
        const int loc  = cc - wreg * 768;
        bOff[r] = wreg * 86016 + loc * 8;      // + kk*6144 at stage time
    }

    // zero A-buffer (pads stay 0 forever), then stage x slice t=0
    for (int i = tid; i < PROWS * PLDA; i += 512) Ab[i] = 0;
    __syncthreads();
    for (int i = tid; i < PROWS * 69; i += 512) {
        const int r = i / 69, f = i - r * 69;
        Ab[r * PLDA + f] = f2bf(x[((size_t)(brow + r) * 7 + 0) * 69 + f]);
    }

    float creg[2][3][4] = {};   // cell state: [mi][a][r] for unit (3w+a)*16+lm
    float bI[3][4];             // bias: [a][gate]

    for (int s = 0; s < 14; ++s) {
        const bool enc = (s < 7);
        const int t = enc ? s : s - 7;
        const unsigned short* Wt = enc ? WtE : WtD;

        if (s == 0 || s == 7) {
            const float* bsrc = enc ? bIE : bID;
            #pragma unroll
            for (int a = 0; a < 3; ++a)
                #pragma unroll
                for (int g = 0; g < 4; ++g)
                    bI[a][g] = bsrc[(3 * w + a) * 64 + g * 16 + lm];
        }

        STAGEW(0)
        __syncthreads();   // Bs[kk=0] DMA'd (vmcnt0 auto) + Ab fully written

        f32x4 acc[2][12] = {};
        #pragma unroll 1
        for (int kk = 0; kk < 14; ++kk) {
            bf16x8 bR[12], aF[2];
            LOADB_LDS(bR)
            LOADA(aF, kk)
            __syncthreads();              // all waves done reading Bs
            if (kk < 13) STAGEW(kk + 1)   // DMA next slice (overlaps MFMA)
            MFMA12(aF, bR)
            if (kk < 13) __syncthreads(); // stage complete before next reads
        }

        // epilogue: gates -> c (regs) -> h -> Ab[hoff+u] (+ dcd in dec phase)
        const int hoff = (s < 6) ? 69 : 45;   // layout of step s+1
        #pragma unroll
        for (int mi = 0; mi < 2; ++mi)
            #pragma unroll
            for (int a = 0; a < 3; ++a) {
                const int u = (3 * w + a) * 16 + lm;
                const bool uok = (u < 356);
                #pragma unroll
                for (int r = 0; r < 4; ++r) {
                    const float zi = acc[mi][a * 4 + 0][r] + bI[a][0];
                    const float zf = acc[mi][a * 4 + 1][r] + bI[a][1];
                    const float zg = acc[mi][a * 4 + 2][r] + bI[a][2];
                    const float zo = acc[mi][a * 4 + 3][r] + bI[a][3];
                    const float cn = sigf(zf) * creg[mi][a][r]
                                   + sigf(zi) * tanhfast(zg);
                    creg[mi][a][r] = cn;
                    const unsigned short hb = f2bf(sigf(zo) * tanhfast(cn));
                    const int rl = mi * 16 + quad * 4 + r;
                    if (uok) {
                        if (s < 13) Ab[rl * PLDA + hoff + u] = hb;
                        if (!enc)
                            dcd[(size_t)(brow + rl) * 2496 + t * 356 + u] = hb;
                    }
                }
            }

        // stage x/m slice for step s+1 (disjoint from h region)
        const int sn = s + 1;
        if (sn < 7) {
            for (int i = tid; i < PROWS * 69; i += 512) {
                const int r = i / 69, f = i - r * 69;
                Ab[r * PLDA + f] =
                    f2bf(x[((size_t)(brow + r) * 7 + sn) * 69 + f]);
            }
        } else if (sn < 14) {
            for (int i = tid; i < PROWS * 45; i += 512) {
                const int r = i / 45, f = i - r * 45;
                Ab[r * PLDA + f] =
                    f2bf(m[((size_t)(brow + r) * 7 + (sn - 7)) * 45 + f]);
            }
        }
    }
}

// ---- MLP GEMM machinery (unchanged, proven) ----

#define STAGE(A_, Bt_, K_, k0_, b_)                                            \
    {                                                                          \
        const int row = tid >> 2, kc = tid & 3;                                \
        gll16((A_)  + (size_t)(m0 + row) * (K_) + (k0_) + kc * 8,              \
              (void*)&As[b_][tid * 8]);                                        \
        gll16((Bt_) + (size_t)(n0 + row) * (K_) + (k0_) + kc * 8,              \
              (void*)&Bs[b_][tid * 8]);                                        \
    }

#define GEMM_CORE(A_, Bt_, K_)                                                 \
    STAGE(A_, Bt_, K_, 0, 0)                                                   \
    {                                                                          \
        const int niter = (K_) / 32;                                           \
        for (int it = 0; it < niter; ++it) {                                   \
            __syncthreads();                                                   \
            if (it + 1 < niter) {                                              \
                const int kn = (it + 1) * 32, bn = (it + 1) & 1;               \
                STAGE(A_, Bt_, K_, kn, bn)                                     \
            }                                                                  \
            const unsigned short* Asb = As[it & 1];                            \
            const unsigned short* Bsb = Bs[it & 1];                            \
            bf16x8 aF[2], bF[4];                                               \
            _Pragma("unroll")                                                  \
            for (int mi = 0; mi < 2; ++mi)                                     \
                aF[mi] = *(const bf16x8*)(Asb + (wr*32 + mi*16 + lm)*32 + quad*8);\
            _Pragma("unroll")                                                  \
            for (int ni = 0; ni < 4; ++ni)                                     \
                bF[ni] = *(const bf16x8*)(Bsb + (wc*64 + ni*16 + lm)*32 + quad*8);\
            _Pragma("unroll")                                                  \
            for (int mi = 0; mi < 2; ++mi)                                     \
                _Pragma("unroll")                                              \
                for (int ni = 0; ni < 4; ++ni)                                 \
                    acc[mi][ni] = __builtin_amdgcn_mfma_f32_16x16x32_bf16(     \
                        aF[mi], bF[ni], acc[mi][ni], 0, 0, 0);                 \
        }                                                                      \
    }

#define GEMM_PREAMBLE                                                          \
    __shared__ __attribute__((aligned(16))) unsigned short As[2][128 * 32];    \
    __shared__ __attribute__((aligned(16))) unsigned short Bs[2][128 * 32];    \
    const int tid  = threadIdx.x;                                              \
    const int lane = tid & 63;                                                 \
    const int w    = tid >> 6;          /* 0..7 */                             \
    const int wr   = w >> 1, wc = w & 1; /* 4x2 wave grid */                   \
    const int lm   = lane & 15, quad = lane >> 4;                              \
    const int m0   = blockIdx.x * 128, n0 = blockIdx.y * 128;                  \
    f32x4 acc[2][4] = {};

template <int EPI, int OUT_BF16, int NGUARD>
__global__ __launch_bounds__(512, 6)
void gemm_mfma(const unsigned short* __restrict__ A,
               const unsigned short* __restrict__ Bt,
               const float* __restrict__ bias,
               void* __restrict__ Cv, int ldc, int Nreal, int K)
{
    GEMM_PREAMBLE
    GEMM_CORE(A, Bt, K)
    #pragma unroll
    for (int mi = 0; mi < 2; ++mi)
        #pragma unroll
        for (int r = 0; r < 4; ++r) {
            const size_t row = m0 + wr * 32 + mi * 16 + quad * 4 + r;
            #pragma unroll
            for (int ni = 0; ni < 4; ++ni) {
                const int col = n0 + wc * 64 + ni * 16 + lm;
                if (!NGUARD || col < Nreal) {
                    float v = acc[mi][ni][r] + bias[col];
                    if (EPI == EPI_RELU) v = fmaxf(v, 0.f);
                    if (EPI == EPI_TANH) v = tanhfast(v);
                    if (OUT_BF16) ((unsigned short*)Cv)[row * ldc + col] = f2bf(v);
                    else          ((float*)Cv)[row * ldc + col] = v;
                }
            }
        }
}

// ---- LSTM weight pack (enc+dec in one launch; blockIdx.y selects) ----
// New contiguous-fragment layout:
//   elem(np, k) -> ((w*14+kk)*12+ni)*512 + lm*32 + kq
// where np = w*192 + ni*16 + lm, k = kk*32 + kq. Kp=448 for both LSTMs
// (dec rows k>=401 zero-padded).
struct PackArgs {
    const float *Wa0, *Wb0, *bias0; unsigned short* Wt0; float* bI0; int K10, K0, Kp0;
    const float *Wa1, *Wb1, *bias1; unsigned short* Wt1; float* bI1; int K11, K1, Kp1;
};
__global__ void pack_lstm2(PackArgs p)
{
    const float* Wa  = blockIdx.y ? p.Wa1  : p.Wa0;
    const float* Wb  = blockIdx.y ? p.Wb1  : p.Wb0;
    const float* bias= blockIdx.y ? p.bias1: p.bias0;
    unsigned short* Wt = blockIdx.y ? p.Wt1 : p.Wt0;
    float* biasI = blockIdx.y ? p.bI1 : p.bI0;
    const int K1 = blockIdx.y ? p.K11 : p.K10;
    const int K  = blockIdx.y ? p.K1  : p.K0;
    const int Kp = blockIdx.y ? p.Kp1 : p.Kp0;
    const int idx = blockIdx.x * 256 + threadIdx.x;
    if (idx >= 1536 * Kp) return;
    const int np = idx / Kp, k = idx - np * Kp;
    const int ub = np >> 6, g = (np >> 4) & 3, ul = np & 15;
    const int u = ub * 16 + ul;
    const bool valid = (u < 356);
    const int norig = g * 356 + u;
    float v = 0.f;
    if (valid && k < K)
        v = (k < K1) ? Wa[(size_t)k * 1424 + norig]
                     : Wb[(size_t)(k - K1) * 1424 + norig];
    // new layout
    const int wv = np / 192, rem = np - wv * 192;
    const int ni = rem >> 4, lmv = rem & 15;
    const int kkv = k >> 5, kq = k & 31;
    Wt[(size_t)((wv * 14 + kkv) * 12 + ni) * 512 + lmv * 32 + kq] = f2bf(v);
    if (k == 0) biasI[np] = valid ? bias[norig] : 0.f;
}

// ---- MLP weight transpose+pack (fp32 [K][N] -> bf16 [Np][Kp]) ----
__global__ void transpose_pack(const float* __restrict__ W, int K, int N,
                               unsigned short* __restrict__ Wt, int Kp, int Np)
{
    __shared__ float t[32][33];
    const int n0 = blockIdx.x * 32, k0 = blockIdx.y * 32;
    const int tx = threadIdx.x, ty = threadIdx.y;
    #pragma unroll
    for (int r = 0; r < 4; ++r) {
        const int k = k0 + ty + 8 * r, n = n0 + tx;
        t[ty + 8 * r][tx] = (k < K && n < N) ? W[(size_t)k * N + n] : 0.f;
    }
    __syncthreads();
    #pragma unroll
    for (int r = 0; r < 4; ++r) {
        const int k = k0 + tx, n = n0 + ty + 8 * r;
        if (k < Kp && n < Np) Wt[(size_t)n * Kp + k] = f2bf(t[tx][ty + 8 * r]);
    }
}

// three 1024x1024 transposes in one launch (blockIdx.z selects)
struct WP3 { const float *s0, *s1, *s2; unsigned short *d0, *d1, *d2; };
__global__ void transpose_pack3(WP3 p)
{
    __shared__ float t[32][33];
    const float* W = (blockIdx.z == 0) ? p.s0 : (blockIdx.z == 1) ? p.s1 : p.s2;
    unsigned short* Wt = (blockIdx.z == 0) ? p.d0 : (blockIdx.z == 1) ? p.d1 : p.d2;
    const int n0 = blockIdx.x * 32, k0 = blockIdx.y * 32;
    const int tx = threadIdx.x, ty = threadIdx.y;
    #pragma unroll
    for (int r = 0; r < 4; ++r)
        t[ty + 8 * r][tx] = W[(size_t)(k0 + ty + 8 * r) * 1024 + n0 + tx];
    __syncthreads();
    #pragma unroll
    for (int r = 0; r < 4; ++r)
        Wt[(size_t)(n0 + ty + 8 * r) * 1024 + k0 + tx] = f2bf(t[tx][ty + 8 * r]);
}

// ---- zero dcd pad cols (2492..2495 of each row) ----
__global__ void zero_dcd_pad(unsigned short* __restrict__ dcd)
{
    const int i = blockIdx.x * 256 + threadIdx.x;
    if (i < 8192 * 4) dcd[(size_t)(i >> 2) * 2496 + 2492 + (i & 3)] = 0;
}

extern "C" void kernel_launch(void* const* d_in, const int* in_sizes, int n_in,
                              void* d_out, int out_size, void* d_ws, size_t ws_size,
                              hipStream_t stream)
{
    const float* x     = (const float*)d_in[0];
    const float* m     = (const float*)d_in[1];
    const float* enc_W = (const float*)d_in[2];
    const float* enc_U = (const float*)d_in[3];
    const float* enc_b = (const float*)d_in[4];
    const float* dec_W = (const float*)d_in[5];
    const float* dec_Um= (const float*)d_in[6];
    const float* dec_b = (const float*)d_in[7];
    const float* W_map = (const float*)d_in[8];
    const float* b_map = (const float*)d_in[9];
    const float* W1    = (const float*)d_in[10];
    const float* b1    = (const float*)d_in[11];
    const float* W2    = (const float*)d_in[12];
    const float* b2    = (const float*)d_in[13];
    const float* W3    = (const float*)d_in[14];
    const float* b3    = (const float*)d_in[15];
    const float* W_out = (const float*)d_in[16];
    const float* b_out = (const float*)d_in[17];
    float* out = (float*)d_out;

    const int B = 8192, FE = 69, FD = 45;
    const int KMP = 2496;

    char* ws = (char*)d_ws;
    size_t off = 0;
    auto alloc = [&](size_t bytes) -> void* {
        void* p = ws + off; off = (off + bytes + 255) & ~(size_t)255; return p;
    };
    unsigned short* WtE = (unsigned short*)alloc((size_t)1536 * 448 * 2);
    unsigned short* WtD = (unsigned short*)alloc((size_t)1536 * 448 * 2);
    unsigned short* WtM = (unsigned short*)alloc((size_t)1024 * KMP * 2);
    unsigned short* Wt1 = (unsigned short*)alloc((size_t)1024 * 1024 * 2);
    unsigned short* Wt2 = (unsigned short*)alloc((size_t)1024 * 1024 * 2);
    unsigned short* Wt3 = (unsigned short*)alloc((size_t)1024 * 1024 * 2);
    unsigned short* WtO = (unsigned short*)alloc((size_t)256 * 1024 * 2);
    float* bIE = (float*)alloc(1536 * 4);
    float* bID = (float*)alloc(1536 * 4);
    unsigned short* dcd = (unsigned short*)alloc((size_t)B * KMP * 2);
    unsigned short* a1  = (unsigned short*)alloc((size_t)B * 1024 * 2);
    unsigned short* a2  = (unsigned short*)alloc((size_t)B * 1024 * 2);

    // ---- weight packing (both LSTMs padded to Kp=448, contiguous frags) ----
    PackArgs pa{enc_W, enc_U, enc_b, WtE, bIE, FE, FE + 356, 448,
                dec_W, dec_Um, dec_b, WtD, bID, FD, FD + 356, 448};
    pack_lstm2<<<dim3((1536 * 448 + 255) / 256, 2), 256, 0, stream>>>(pa);
    const dim3 tb(32, 8);
    transpose_pack<<<dim3(1024 / 32, KMP / 32), tb, 0, stream>>>(
        W_map, 2492, 1024, WtM, KMP, 1024);
    WP3 p3{W1, W2, W3, Wt1, Wt2, Wt3};
    transpose_pack3<<<dim3(32, 32, 3), tb, 0, stream>>>(p3);
    transpose_pack<<<dim3(256 / 32, 1024 / 32), tb, 0, stream>>>(
        W_out, 1024, 168, WtO, 1024, 256);
    zero_dcd_pad<<<(8192 * 4 + 255) / 256, 256, 0, stream>>>(dcd);

    // ---- persistent LSTM: one plain launch, zero grid sync ----
    lstm_persist<<<256, 512, 0, stream>>>(x, m, WtE, WtD, bIE, bID, dcd);

    // ---- MLP head ----
    gemm_mfma<EPI_RELU, 1, 0><<<dim3(64, 8), 512, 0, stream>>>(
        dcd, WtM, b_map, a1, 1024, 1024, KMP);
    gemm_mfma<EPI_TANH, 1, 0><<<dim3(64, 8), 512, 0, stream>>>(
        a1, Wt1, b1, a2, 1024, 1024, 1024);
    gemm_mfma<EPI_TANH, 1, 0><<<dim3(64, 8), 512, 0, stream>>>(
        a2, Wt2, b2, a1, 1024, 1024, 1024);
    gemm_mfma<EPI_TANH, 1, 0><<<dim3(64, 8), 512, 0, stream>>>(
        a1, Wt3, b3, a2, 1024, 1024, 1024);
    gemm_mfma<EPI_NONE, 0, 1><<<dim3(64, 2), 512, 0, stream>>>(
        a2, WtO, b_out, out, 168, 168, 1024);
}

// Round 10
// 621.784 us; speedup vs baseline: 1.5373x; 1.2504x over previous
//
#include <hip/hip_runtime.h>
#include <math.h>

// ---------------------------------------------------------------------------
// Round 19: fix r16's two measured costs on its PROVEN-RUNNABLE structure.
// (r17/r18 direct-to-VGPR streaming failed the container twice -> abandoned
// as a toolchain hazard.) Changes vs r16:
//  1. kk-major + lane-major weight pack: slice kk is 96KB contiguous laid
//     out exactly as Bs; STAGEW = linear tid*16B DMA (no bOff table);
//     fragment read = lane*16B ds_read_b128 -> conflict-free (was 2.25e7
//     bank conflicts).
//  2. per-block kk staggering (kk0 = blockIdx.x % 14): all 32 CUs of an XCD
//     no longer read the SAME 96KB slice in lockstep -> kills L2 hot-banking
//     (r16 ran 4x above the L2-BW floor). fp32 kk-order change = rounding
//     noise only.
// Everything else byte-identical to r16 (ran at 548us chain / 777 total).
// ---------------------------------------------------------------------------

using bf16x8 = __attribute__((ext_vector_type(8))) short;
using f32x4  = __attribute__((ext_vector_type(4))) float;

enum { EPI_NONE = 0, EPI_RELU = 1, EPI_TANH = 2 };

__device__ inline unsigned short f2bf(float f) {
    union { float f; unsigned u; } v; v.f = f;
    unsigned r = v.u + 0x7FFFu + ((v.u >> 16) & 1u);
    return (unsigned short)(r >> 16);
}
__device__ inline float sigf(float x) {
    return __fdividef(1.f, 1.f + __expf(-x));
}
__device__ inline float tanhfast(float x) {
    return 1.f - __fdividef(2.f, 1.f + __expf(2.f * x));
}

__device__ inline void gll16(const void* g, void* l) {
    __builtin_amdgcn_global_load_lds(
        (const __attribute__((address_space(1))) unsigned int*)(uintptr_t)g,
        (__attribute__((address_space(3))) unsigned int*)(unsigned int)(uintptr_t)l,
        16, 0, 0);
}

// ---------------------------------------------------------------------------
// Persistent LSTM: grid 256 x 512 threads, 1 block/CU (LDS 124.5 KB).
// Block b owns batch rows [32b, 32b+32). Ab [32][456] bf16 holds x|h.
// Wave w owns packed gate cols [192w,192w+192) = units {48w..48w+47}.
// Weight layout (pack_lstm2): elem(np = w*192+ni*16+lm, k = kk*32+quad*8+j)
// at kk*49152 + (w*12+ni)*512 + (quad*16+lm)*8 + j  -> slice kk = 96KB
// contiguous, identical to the Bs layout. Bs read: lane*16B (conflict-free).
// ---------------------------------------------------------------------------
#define PROWS 32
#define PLDA  456

// stage the 96KB weight slice for K-chunk kkv into Bs (12 linear chunks/thr)
#define STAGEW(kkv)                                                            \
    _Pragma("unroll")                                                          \
    for (int r = 0; r < 12; ++r)                                               \
        gll16(Wt + (size_t)(kkv) * 49152 + (tid + r * 512) * 8,                \
              (void*)&Bs[(tid + r * 512) * 8]);

// load the 12 B-fragments of wave w from Bs (conflict-free ds_read_b128)
#define LOADB_LDS(dst)                                                         \
    _Pragma("unroll")                                                          \
    for (int ni = 0; ni < 12; ++ni)                                            \
        dst[ni] = *(const bf16x8*)&Bs[(w * 12 + ni) * 512 + lane * 8];

// load the 2 A-fragments for K-slice kkv from Ab
#define LOADA(dst, kkv)                                                        \
    _Pragma("unroll")                                                          \
    for (int mi = 0; mi < 2; ++mi)                                             \
        dst[mi] = *(const bf16x8*)&Ab[(mi * 16 + lm) * PLDA + (kkv) * 32       \
                                      + quad * 8];

// 24 MFMAs: acc += aF x bW
#define MFMA12(aF, bW)                                                         \
    _Pragma("unroll")                                                          \
    for (int ni = 0; ni < 12; ++ni) {                                          \
        acc[0][ni] = __builtin_amdgcn_mfma_f32_16x16x32_bf16(                  \
            aF[0], bW[ni], acc[0][ni], 0, 0, 0);                               \
        acc[1][ni] = __builtin_amdgcn_mfma_f32_16x16x32_bf16(                  \
            aF[1], bW[ni], acc[1][ni], 0, 0, 0);                               \
    }

__global__ __attribute__((amdgpu_flat_work_group_size(512, 512),
                          amdgpu_waves_per_eu(2, 2)))
void lstm_persist(const float* __restrict__ x,
                  const float* __restrict__ m,
                  const unsigned short* __restrict__ WtE,
                  const unsigned short* __restrict__ WtD,
                  const float* __restrict__ bIE,
                  const float* __restrict__ bID,
                  unsigned short* __restrict__ dcd)
{
    __shared__ __attribute__((aligned(16))) unsigned short Ab[PROWS * PLDA];
    __shared__ __attribute__((aligned(16))) unsigned short Bs[49152];
    const int tid  = threadIdx.x;
    const int lane = tid & 63;
    const int w    = tid >> 6;           // 0..7
    const int lm   = lane & 15, quad = lane >> 4;
    const int brow = blockIdx.x * PROWS;
    const int kk0  = blockIdx.x % 14;    // per-block kk stagger (L2 spread)

    // zero A-buffer (pads stay 0 forever), then stage x slice t=0
    for (int i = tid; i < PROWS * PLDA; i += 512) Ab[i] = 0;
    __syncthreads();
    for (int i = tid; i < PROWS * 69; i += 512) {
        const int r = i / 69, f = i - r * 69;
        Ab[r * PLDA + f] = f2bf(x[((size_t)(brow + r) * 7 + 0) * 69 + f]);
    }

    float creg[2][3][4] = {};   // cell state: [mi][a][r] for unit (3w+a)*16+lm
    float bI[3][4];             // bias: [a][gate]

    for (int s = 0; s < 14; ++s) {
        const bool enc = (s < 7);
        const int t = enc ? s : s - 7;
        const unsigned short* Wt = enc ? WtE : WtD;

        if (s == 0 || s == 7) {
            const float* bsrc = enc ? bIE : bID;
            #pragma unroll
            for (int a = 0; a < 3; ++a)
                #pragma unroll
                for (int g = 0; g < 4; ++g)
                    bI[a][g] = bsrc[(3 * w + a) * 64 + g * 16 + lm];
        }

        STAGEW(kk0)
        __syncthreads();   // Bs[kk0] DMA'd (vmcnt0 auto) + Ab fully written

        f32x4 acc[2][12] = {};
        #pragma unroll 1
        for (int kk = 0; kk < 14; ++kk) {
            const int kks = kk + kk0 - ((kk + kk0 >= 14) ? 14 : 0);
            bf16x8 bR[12], aF[2];
            LOADB_LDS(bR)
            LOADA(aF, kks)
            __syncthreads();              // all waves done reading Bs
            if (kk < 13) {
                const int kkn = (kks == 13) ? 0 : kks + 1;
                STAGEW(kkn)               // DMA next slice (overlaps MFMA)
            }
            MFMA12(aF, bR)
            if (kk < 13) __syncthreads(); // stage complete before next reads
        }

        // epilogue: gates -> c (regs) -> h -> Ab[hoff+u] (+ dcd in dec phase)
        const int hoff = (s < 6) ? 69 : 45;   // layout of step s+1
        #pragma unroll
        for (int mi = 0; mi < 2; ++mi)
            #pragma unroll
            for (int a = 0; a < 3; ++a) {
                const int u = (3 * w + a) * 16 + lm;
                const bool uok = (u < 356);
                #pragma unroll
                for (int r = 0; r < 4; ++r) {
                    const float zi = acc[mi][a * 4 + 0][r] + bI[a][0];
                    const float zf = acc[mi][a * 4 + 1][r] + bI[a][1];
                    const float zg = acc[mi][a * 4 + 2][r] + bI[a][2];
                    const float zo = acc[mi][a * 4 + 3][r] + bI[a][3];
                    const float cn = sigf(zf) * creg[mi][a][r]
                                   + sigf(zi) * tanhfast(zg);
                    creg[mi][a][r] = cn;
                    const unsigned short hb = f2bf(sigf(zo) * tanhfast(cn));
                    const int rl = mi * 16 + quad * 4 + r;
                    if (uok) {
                        if (s < 13) Ab[rl * PLDA + hoff + u] = hb;
                        if (!enc)
                            dcd[(size_t)(brow + rl) * 2496 + t * 356 + u] = hb;
                    }
                }
            }

        // stage x/m slice for step s+1 (disjoint from h region)
        const int sn = s + 1;
        if (sn < 7) {
            for (int i = tid; i < PROWS * 69; i += 512) {
                const int r = i / 69, f = i - r * 69;
                Ab[r * PLDA + f] =
                    f2bf(x[((size_t)(brow + r) * 7 + sn) * 69 + f]);
            }
        } else if (sn < 14) {
            for (int i = tid; i < PROWS * 45; i += 512) {
                const int r = i / 45, f = i - r * 45;
                Ab[r * PLDA + f] =
                    f2bf(m[((size_t)(brow + r) * 7 + (sn - 7)) * 45 + f]);
            }
        }
    }
}

// ---- MLP GEMM machinery (unchanged, proven) ----

#define STAGE(A_, Bt_, K_, k0_, b_)                                            \
    {                                                                          \
        const int row = tid >> 2, kc = tid & 3;                                \
        gll16((A_)  + (size_t)(m0 + row) * (K_) + (k0_) + kc * 8,              \
              (void*)&As[b_][tid * 8]);                                        \
        gll16((Bt_) + (size_t)(n0 + row) * (K_) + (k0_) + kc * 8,              \
              (void*)&Bs[b_][tid * 8]);                                        \
    }

#define GEMM_CORE(A_, Bt_, K_)                                                 \
    STAGE(A_, Bt_, K_, 0, 0)                                                   \
    {                                                                          \
        const int niter = (K_) / 32;                                           \
        for (int it = 0; it < niter; ++it) {                                   \
            __syncthreads();                                                   \
            if (it + 1 < niter) {                                              \
                const int kn = (it + 1) * 32, bn = (it + 1) & 1;               \
                STAGE(A_, Bt_, K_, kn, bn)                                     \
            }                                                                  \
            const unsigned short* Asb = As[it & 1];                            \
            const unsigned short* Bsb = Bs[it & 1];                            \
            bf16x8 aF[2], bF[4];                                               \
            _Pragma("unroll")                                                  \
            for (int mi = 0; mi < 2; ++mi)                                     \
                aF[mi] = *(const bf16x8*)(Asb + (wr*32 + mi*16 + lm)*32 + quad*8);\
            _Pragma("unroll")                                                  \
            for (int ni = 0; ni < 4; ++ni)                                     \
                bF[ni] = *(const bf16x8*)(Bsb + (wc*64 + ni*16 + lm)*32 + quad*8);\
            _Pragma("unroll")                                                  \
            for (int mi = 0; mi < 2; ++mi)                                     \
                _Pragma("unroll")                                              \
                for (int ni = 0; ni < 4; ++ni)                                 \
                    acc[mi][ni] = __builtin_amdgcn_mfma_f32_16x16x32_bf16(     \
                        aF[mi], bF[ni], acc[mi][ni], 0, 0, 0);                 \
        }                                                                      \
    }

#define GEMM_PREAMBLE                                                          \
    __shared__ __attribute__((aligned(16))) unsigned short As[2][128 * 32];    \
    __shared__ __attribute__((aligned(16))) unsigned short Bs[2][128 * 32];    \
    const int tid  = threadIdx.x;                                              \
    const int lane = tid & 63;                                                 \
    const int w    = tid >> 6;          /* 0..7 */                             \
    const int wr   = w >> 1, wc = w & 1; /* 4x2 wave grid */                   \
    const int lm   = lane & 15, quad = lane >> 4;                              \
    const int m0   = blockIdx.x * 128, n0 = blockIdx.y * 128;                  \
    f32x4 acc[2][4] = {};

template <int EPI, int OUT_BF16, int NGUARD>
__global__ __launch_bounds__(512, 6)
void gemm_mfma(const unsigned short* __restrict__ A,
               const unsigned short* __restrict__ Bt,
               const float* __restrict__ bias,
               void* __restrict__ Cv, int ldc, int Nreal, int K)
{
    GEMM_PREAMBLE
    GEMM_CORE(A, Bt, K)
    #pragma unroll
    for (int mi = 0; mi < 2; ++mi)
        #pragma unroll
        for (int r = 0; r < 4; ++r) {
            const size_t row = m0 + wr * 32 + mi * 16 + quad * 4 + r;
            #pragma unroll
            for (int ni = 0; ni < 4; ++ni) {
                const int col = n0 + wc * 64 + ni * 16 + lm;
                if (!NGUARD || col < Nreal) {
                    float v = acc[mi][ni][r] + bias[col];
                    if (EPI == EPI_RELU) v = fmaxf(v, 0.f);
                    if (EPI == EPI_TANH) v = tanhfast(v);
                    if (OUT_BF16) ((unsigned short*)Cv)[row * ldc + col] = f2bf(v);
                    else          ((float*)Cv)[row * ldc + col] = v;
                }
            }
        }
}

// ---- LSTM weight pack (enc+dec in one launch; blockIdx.y selects) ----
// kk-major, lane-major fragment layout:
//   elem(np, k) -> kk*49152 + (w*12+ni)*512 + (quad*16+lm)*8 + j   (shorts)
// where np = w*192+ni*16+lm, k = kk*32+quad*8+j. Kp=448 both (dec k>=401
// zero-padded).
struct PackArgs {
    const float *Wa0, *Wb0, *bias0; unsigned short* Wt0; float* bI0; int K10, K0, Kp0;
    const float *Wa1, *Wb1, *bias1; unsigned short* Wt1; float* bI1; int K11, K1, Kp1;
};
__global__ void pack_lstm2(PackArgs p)
{
    const float* Wa  = blockIdx.y ? p.Wa1  : p.Wa0;
    const float* Wb  = blockIdx.y ? p.Wb1  : p.Wb0;
    const float* bias= blockIdx.y ? p.bias1: p.bias0;
    unsigned short* Wt = blockIdx.y ? p.Wt1 : p.Wt0;
    float* biasI = blockIdx.y ? p.bI1 : p.bI0;
    const int K1 = blockIdx.y ? p.K11 : p.K10;
    const int K  = blockIdx.y ? p.K1  : p.K0;
    const int Kp = blockIdx.y ? p.Kp1 : p.Kp0;
    const int idx = blockIdx.x * 256 + threadIdx.x;
    if (idx >= 1536 * Kp) return;
    const int np = idx / Kp, k = idx - np * Kp;
    const int ub = np >> 6, g = (np >> 4) & 3, ul = np & 15;
    const int u = ub * 16 + ul;
    const bool valid = (u < 356);
    const int norig = g * 356 + u;
    float v = 0.f;
    if (valid && k < K)
        v = (k < K1) ? Wa[(size_t)k * 1424 + norig]
                     : Wb[(size_t)(k - K1) * 1424 + norig];
    // kk-major, lane-major fragment layout
    const int wv = np / 192, rem = np - wv * 192;
    const int ni = rem >> 4, lmv = rem & 15;
    const int kkv = k >> 5, kq = k & 31;
    const int qd = kq >> 3, j = kq & 7;
    Wt[(size_t)kkv * 49152 + (size_t)(wv * 12 + ni) * 512 + (qd * 16 + lmv) * 8 + j]
        = f2bf(v);
    if (k == 0) biasI[np] = valid ? bias[norig] : 0.f;
}

// ---- MLP weight transpose+pack (fp32 [K][N] -> bf16 [Np][Kp]) ----
__global__ void transpose_pack(const float* __restrict__ W, int K, int N,
                               unsigned short* __restrict__ Wt, int Kp, int Np)
{
    __shared__ float t[32][33];
    const int n0 = blockIdx.x * 32, k0 = blockIdx.y * 32;
    const int tx = threadIdx.x, ty = threadIdx.y;
    #pragma unroll
    for (int r = 0; r < 4; ++r) {
        const int k = k0 + ty + 8 * r, n = n0 + tx;
        t[ty + 8 * r][tx] = (k < K && n < N) ? W[(size_t)k * N + n] : 0.f;
    }
    __syncthreads();
    #pragma unroll
    for (int r = 0; r < 4; ++r) {
        const int k = k0 + tx, n = n0 + ty + 8 * r;
        if (k < Kp && n < Np) Wt[(size_t)n * Kp + k] = f2bf(t[tx][ty + 8 * r]);
    }
}

// three 1024x1024 transposes in one launch (blockIdx.z selects)
struct WP3 { const float *s0, *s1, *s2; unsigned short *d0, *d1, *d2; };
__global__ void transpose_pack3(WP3 p)
{
    __shared__ float t[32][33];
    const float* W = (blockIdx.z == 0) ? p.s0 : (blockIdx.z == 1) ? p.s1 : p.s2;
    unsigned short* Wt = (blockIdx.z == 0) ? p.d0 : (blockIdx.z == 1) ? p.d1 : p.d2;
    const int n0 = blockIdx.x * 32, k0 = blockIdx.y * 32;
    const int tx = threadIdx.x, ty = threadIdx.y;
    #pragma unroll
    for (int r = 0; r < 4; ++r)
        t[ty + 8 * r][tx] = W[(size_t)(k0 + ty + 8 * r) * 1024 + n0 + tx];
    __syncthreads();
    #pragma unroll
    for (int r = 0; r < 4; ++r)
        Wt[(size_t)(n0 + ty + 8 * r) * 1024 + k0 + tx] = f2bf(t[tx][ty + 8 * r]);
}

// ---- zero dcd pad cols (2492..2495 of each row) ----
__global__ void zero_dcd_pad(unsigned short* __restrict__ dcd)
{
    const int i = blockIdx.x * 256 + threadIdx.x;
    if (i < 8192 * 4) dcd[(size_t)(i >> 2) * 2496 + 2492 + (i & 3)] = 0;
}

extern "C" void kernel_launch(void* const* d_in, const int* in_sizes, int n_in,
                              void* d_out, int out_size, void* d_ws, size_t ws_size,
                              hipStream_t stream)
{
    const float* x     = (const float*)d_in[0];
    const float* m     = (const float*)d_in[1];
    const float* enc_W = (const float*)d_in[2];
    const float* enc_U = (const float*)d_in[3];
    const float* enc_b = (const float*)d_in[4];
    const float* dec_W = (const float*)d_in[5];
    const float* dec_Um= (const float*)d_in[6];
    const float* dec_b = (const float*)d_in[7];
    const float* W_map = (const float*)d_in[8];
    const float* b_map = (const float*)d_in[9];
    const float* W1    = (const float*)d_in[10];
    const float* b1    = (const float*)d_in[11];
    const float* W2    = (const float*)d_in[12];
    const float* b2    = (const float*)d_in[13];
    const float* W3    = (const float*)d_in[14];
    const float* b3    = (const float*)d_in[15];
    const float* W_out = (const float*)d_in[16];
    const float* b_out = (const float*)d_in[17];
    float* out = (float*)d_out;

    const int B = 8192, FE = 69, FD = 45;
    const int KMP = 2496;

    char* ws = (char*)d_ws;
    size_t off = 0;
    auto alloc = [&](size_t bytes) -> void* {
        void* p = ws + off; off = (off + bytes + 255) & ~(size_t)255; return p;
    };
    unsigned short* WtE = (unsigned short*)alloc((size_t)1536 * 448 * 2);
    unsigned short* WtD = (unsigned short*)alloc((size_t)1536 * 448 * 2);
    unsigned short* WtM = (unsigned short*)alloc((size_t)1024 * KMP * 2);
    unsigned short* Wt1 = (unsigned short*)alloc((size_t)1024 * 1024 * 2);
    unsigned short* Wt2 = (unsigned short*)alloc((size_t)1024 * 1024 * 2);
    unsigned short* Wt3 = (unsigned short*)alloc((size_t)1024 * 1024 * 2);
    unsigned short* WtO = (unsigned short*)alloc((size_t)256 * 1024 * 2);
    float* bIE = (float*)alloc(1536 * 4);
    float* bID = (float*)alloc(1536 * 4);
    unsigned short* dcd = (unsigned short*)alloc((size_t)B * KMP * 2);
    unsigned short* a1  = (unsigned short*)alloc((size_t)B * 1024 * 2);
    unsigned short* a2  = (unsigned short*)alloc((size_t)B * 1024 * 2);

    // ---- weight packing (Kp=448 both, kk-major lane-major frags) ----
    PackArgs pa{enc_W, enc_U, enc_b, WtE, bIE, FE, FE + 356, 448,
                dec_W, dec_Um, dec_b, WtD, bID, FD, FD + 356, 448};
    pack_lstm2<<<dim3((1536 * 448 + 255) / 256, 2), 256, 0, stream>>>(pa);
    const dim3 tb(32, 8);
    transpose_pack<<<dim3(1024 / 32, KMP / 32), tb, 0, stream>>>(
        W_map, 2492, 1024, WtM, KMP, 1024);
    WP3 p3{W1, W2, W3, Wt1, Wt2, Wt3};
    transpose_pack3<<<dim3(32, 32, 3), tb, 0, stream>>>(p3);
    transpose_pack<<<dim3(256 / 32, 1024 / 32), tb, 0, stream>>>(
        W_out, 1024, 168, WtO, 1024, 256);
    zero_dcd_pad<<<(8192 * 4 + 255) / 256, 256, 0, stream>>>(dcd);

    // ---- persistent LSTM: one plain launch, zero grid sync ----
    lstm_persist<<<256, 512, 0, stream>>>(x, m, WtE, WtD, bIE, bID, dcd);

    // ---- MLP head ----
    gemm_mfma<EPI_RELU, 1, 0><<<dim3(64, 8), 512, 0, stream>>>(
        dcd, WtM, b_map, a1, 1024, 1024, KMP);
    gemm_mfma<EPI_TANH, 1, 0><<<dim3(64, 8), 512, 0, stream>>>(
        a1, Wt1, b1, a2, 1024, 1024, 1024);
    gemm_mfma<EPI_TANH, 1, 0><<<dim3(64, 8), 512, 0, stream>>>(
        a2, Wt2, b2, a1, 1024, 1024, 1024);
    gemm_mfma<EPI_TANH, 1, 0><<<dim3(64, 8), 512, 0, stream>>>(
        a1, Wt3, b3, a2, 1024, 1024, 1024);
    gemm_mfma<EPI_NONE, 0, 1><<<dim3(64, 2), 512, 0, stream>>>(
        a2, WtO, b_out, out, 168, 168, 1024);
}

// Round 11
// 570.225 us; speedup vs baseline: 1.6763x; 1.0904x over previous
//
#include <hip/hip_runtime.h>
#include <math.h>

// ---------------------------------------------------------------------------
// Round 20: barrier-free kk loop via per-wave private staging + counted
// vmcnt. r19 post-mortem: conflicts fixed (2.25e7->3.2e6), chain 548->404us,
// but still 2 block barriers per kk (28/step) each with an implicit
// vmcnt(0) DRAIN -> the m97-structure stall, 2.6x above the ~154us L2-BW
// floor. Insight: wave w only reads its OWN 12KB of Bs -> stage per-wave,
// sync per-wave with counted s_waitcnt vmcnt(8) (T4: never drain to 0 in
// the loop), NO barriers in the kk loop. 3 rotating 4KB buffers/wave
// (96KB total), 2-chunk-deep pipeline, part index statically unrolled
// (rule #20), sched_barrier(0) after each waitcnt (rule #18).
// Block barriers remain only at step boundaries (2/step, for Ab).
// ---------------------------------------------------------------------------

using bf16x8 = __attribute__((ext_vector_type(8))) short;
using f32x4  = __attribute__((ext_vector_type(4))) float;

enum { EPI_NONE = 0, EPI_RELU = 1, EPI_TANH = 2 };

__device__ inline unsigned short f2bf(float f) {
    union { float f; unsigned u; } v; v.f = f;
    unsigned r = v.u + 0x7FFFu + ((v.u >> 16) & 1u);
    return (unsigned short)(r >> 16);
}
__device__ inline float sigf(float x) {
    return __fdividef(1.f, 1.f + __expf(-x));
}
__device__ inline float tanhfast(float x) {
    return 1.f - __fdividef(2.f, 1.f + __expf(2.f * x));
}

__device__ inline void gll16(const void* g, void* l) {
    __builtin_amdgcn_global_load_lds(
        (const __attribute__((address_space(1))) unsigned int*)(uintptr_t)g,
        (__attribute__((address_space(3))) unsigned int*)(unsigned int)(uintptr_t)l,
        16, 0, 0);
}

// ---------------------------------------------------------------------------
// Persistent LSTM: grid 256 x 512 threads, 1 block/CU (LDS 124.5 KB).
// Block b owns batch rows [32b, 32b+32). Ab [32][456] bf16 holds x|h.
// Wave w owns packed gate cols [192w,192w+192) = units {48w..48w+47}.
// Weight layout (pack_lstm2): elem(np = w*192+ni*16+lm, k = kk*32+quad*8+j)
// at kk*49152 + (w*12+ni)*512 + (quad*16+lm)*8 + j.
// Bs: per-wave 3 rotating buffers of 4 fragments (4KB):
//   Bs[((w*3+buf)*4+q)*512 + lane*8]  (write via gll16, read lane*16B).
// ---------------------------------------------------------------------------
#define PROWS 32
#define PLDA  456

// stage chunk (kkv, partv) -> per-wave buffer bufv (4 x gll16, 4KB)
#define STAGE_CHUNK(bufv, kkv, partv)                                          \
    _Pragma("unroll")                                                          \
    for (int q = 0; q < 4; ++q)                                                \
        gll16(Wt + (size_t)(kkv) * 49152 + (w * 12 + (partv) * 4 + q) * 512    \
                  + lane * 8,                                                  \
              (void*)&Bs[((w * 3 + (bufv)) * 4 + q) * 512 + lane * 8]);

// read the 4 fragments of per-wave buffer bufv (conflict-free lane*16B)
#define LOADB4(dst, bufv)                                                      \
    _Pragma("unroll")                                                          \
    for (int q = 0; q < 4; ++q)                                                \
        dst[q] = *(const bf16x8*)&Bs[((w * 3 + (bufv)) * 4 + q) * 512          \
                                     + lane * 8];

// load the 2 A-fragments for K-slice kkv from Ab
#define LOADA(dst, kkv)                                                        \
    _Pragma("unroll")                                                          \
    for (int mi = 0; mi < 2; ++mi)                                             \
        dst[mi] = *(const bf16x8*)&Ab[(mi * 16 + lm) * PLDA + (kkv) * 32       \
                                      + quad * 8];

// 8 MFMAs for part partv (LITERAL 0/1/2 -> static acc indices)
#define MFMA8(partv, bRv)                                                      \
    _Pragma("unroll")                                                          \
    for (int q = 0; q < 4; ++q) {                                              \
        acc[0][(partv) * 4 + q] = __builtin_amdgcn_mfma_f32_16x16x32_bf16(     \
            aF[0], bRv[q], acc[0][(partv) * 4 + q], 0, 0, 0);                  \
        acc[1][(partv) * 4 + q] = __builtin_amdgcn_mfma_f32_16x16x32_bf16(     \
            aF[1], bRv[q], acc[1][(partv) * 4 + q], 0, 0, 0);                  \
    }

#define VMWAIT(n)                                                              \
    asm volatile("s_waitcnt vmcnt(" #n ")" ::: "memory");                      \
    __builtin_amdgcn_sched_barrier(0);

__global__ __attribute__((amdgpu_flat_work_group_size(512, 512),
                          amdgpu_waves_per_eu(2, 2)))
void lstm_persist(const float* __restrict__ x,
                  const float* __restrict__ m,
                  const unsigned short* __restrict__ WtE,
                  const unsigned short* __restrict__ WtD,
                  const float* __restrict__ bIE,
                  const float* __restrict__ bID,
                  unsigned short* __restrict__ dcd)
{
    __shared__ __attribute__((aligned(16))) unsigned short Ab[PROWS * PLDA];
    __shared__ __attribute__((aligned(16))) unsigned short Bs[49152];
    const int tid  = threadIdx.x;
    const int lane = tid & 63;
    const int w    = tid >> 6;           // 0..7
    const int lm   = lane & 15, quad = lane >> 4;
    const int brow = blockIdx.x * PROWS;
    const int kk0  = blockIdx.x % 14;    // per-block kk stagger (L2 spread)

    // zero A-buffer (pads stay 0 forever), then stage x slice t=0
    for (int i = tid; i < PROWS * PLDA; i += 512) Ab[i] = 0;
    __syncthreads();
    for (int i = tid; i < PROWS * 69; i += 512) {
        const int r = i / 69, f = i - r * 69;
        Ab[r * PLDA + f] = f2bf(x[((size_t)(brow + r) * 7 + 0) * 69 + f]);
    }

    float creg[2][3][4] = {};   // cell state: [mi][a][r] for unit (3w+a)*16+lm
    float bI[3][4];             // bias: [a][gate]

    for (int s = 0; s < 14; ++s) {
        const bool enc = (s < 7);
        const int t = enc ? s : s - 7;
        const unsigned short* Wt = enc ? WtE : WtD;

        if (s == 0 || s == 7) {
            const float* bsrc = enc ? bIE : bID;
            #pragma unroll
            for (int a = 0; a < 3; ++a)
                #pragma unroll
                for (int g = 0; g < 4; ++g)
                    bI[a][g] = bsrc[(3 * w + a) * 64 + g * 16 + lm];
        }

        __syncthreads();   // Ab (x for s, h from s-1) visible; drains vmcnt

        f32x4 acc[2][12] = {};
        {
            // prologue: chunks 0,1 of kk0 -> bufs 0,1 (8 loads outstanding)
            STAGE_CHUNK(0, kk0, 0)
            STAGE_CHUNK(1, kk0, 1)
            int kkc = kk0;
            #pragma unroll 1
            for (int i = 0; i < 14; ++i) {
                const int kkn = (kkc == 13) ? 0 : kkc + 1;
                bf16x8 aF[2], bR[4];
                // part 0: stage (kkc,2)->buf2; wait chunk(i,0); compute buf0
                STAGE_CHUNK(2, kkc, 2)
                VMWAIT(8)
                LOADA(aF, kkc)
                LOADB4(bR, 0)
                MFMA8(0, bR)
                // part 1: stage (kkn,0)->buf0; wait chunk(i,1); compute buf1
                if (i < 13) {
                    STAGE_CHUNK(0, kkn, 0)
                    VMWAIT(8)
                } else {
                    VMWAIT(4)
                }
                LOADB4(bR, 1)
                MFMA8(1, bR)
                // part 2: stage (kkn,1)->buf1; wait chunk(i,2); compute buf2
                if (i < 13) {
                    STAGE_CHUNK(1, kkn, 1)
                    VMWAIT(8)
                } else {
                    VMWAIT(0)
                }
                LOADB4(bR, 2)
                MFMA8(2, bR)
                kkc = kkn;
            }
        }

        __syncthreads();   // all Ab reads done before h overwrite

        // epilogue: gates -> c (regs) -> h -> Ab[hoff+u] (+ dcd in dec phase)
        const int hoff = (s < 6) ? 69 : 45;   // layout of step s+1
        #pragma unroll
        for (int mi = 0; mi < 2; ++mi)
            #pragma unroll
            for (int a = 0; a < 3; ++a) {
                const int u = (3 * w + a) * 16 + lm;
                const bool uok = (u < 356);
                #pragma unroll
                for (int r = 0; r < 4; ++r) {
                    const float zi = acc[mi][a * 4 + 0][r] + bI[a][0];
                    const float zf = acc[mi][a * 4 + 1][r] + bI[a][1];
                    const float zg = acc[mi][a * 4 + 2][r] + bI[a][2];
                    const float zo = acc[mi][a * 4 + 3][r] + bI[a][3];
                    const float cn = sigf(zf) * creg[mi][a][r]
                                   + sigf(zi) * tanhfast(zg);
                    creg[mi][a][r] = cn;
                    const unsigned short hb = f2bf(sigf(zo) * tanhfast(cn));
                    const int rl = mi * 16 + quad * 4 + r;
                    if (uok) {
                        if (s < 13) Ab[rl * PLDA + hoff + u] = hb;
                        if (!enc)
                            dcd[(size_t)(brow + rl) * 2496 + t * 356 + u] = hb;
                    }
                }
            }

        // stage x/m slice for step s+1 (disjoint from h region)
        const int sn = s + 1;
        if (sn < 7) {
            for (int i = tid; i < PROWS * 69; i += 512) {
                const int r = i / 69, f = i - r * 69;
                Ab[r * PLDA + f] =
                    f2bf(x[((size_t)(brow + r) * 7 + sn) * 69 + f]);
            }
        } else if (sn < 14) {
            for (int i = tid; i < PROWS * 45; i += 512) {
                const int r = i / 45, f = i - r * 45;
                Ab[r * PLDA + f] =
                    f2bf(m[((size_t)(brow + r) * 7 + (sn - 7)) * 45 + f]);
            }
        }
    }
}

// ---- MLP GEMM machinery (unchanged, proven) ----

#define STAGE(A_, Bt_, K_, k0_, b_)                                            \
    {                                                                          \
        const int row = tid >> 2, kc = tid & 3;                                \
        gll16((A_)  + (size_t)(m0 + row) * (K_) + (k0_) + kc * 8,              \
              (void*)&As[b_][tid * 8]);                                        \
        gll16((Bt_) + (size_t)(n0 + row) * (K_) + (k0_) + kc * 8,              \
              (void*)&Bs[b_][tid * 8]);                                        \
    }

#define GEMM_CORE(A_, Bt_, K_)                                                 \
    STAGE(A_, Bt_, K_, 0, 0)                                                   \
    {                                                                          \
        const int niter = (K_) / 32;                                           \
        for (int it = 0; it < niter; ++it) {                                   \
            __syncthreads();                                                   \
            if (it + 1 < niter) {                                              \
                const int kn = (it + 1) * 32, bn = (it + 1) & 1;               \
                STAGE(A_, Bt_, K_, kn, bn)                                     \
            }                                                                  \
            const unsigned short* Asb = As[it & 1];                            \
            const unsigned short* Bsb = Bs[it & 1];                            \
            bf16x8 aF[2], bF[4];                                               \
            _Pragma("unroll")                                                  \
            for (int mi = 0; mi < 2; ++mi)                                     \
                aF[mi] = *(const bf16x8*)(Asb + (wr*32 + mi*16 + lm)*32 + quad*8);\
            _Pragma("unroll")                                                  \
            for (int ni = 0; ni < 4; ++ni)                                     \
                bF[ni] = *(const bf16x8*)(Bsb + (wc*64 + ni*16 + lm)*32 + quad*8);\
            _Pragma("unroll")                                                  \
            for (int mi = 0; mi < 2; ++mi)                                     \
                _Pragma("unroll")                                              \
                for (int ni = 0; ni < 4; ++ni)                                 \
                    acc[mi][ni] = __builtin_amdgcn_mfma_f32_16x16x32_bf16(     \
                        aF[mi], bF[ni], acc[mi][ni], 0, 0, 0);                 \
        }                                                                      \
    }

#define GEMM_PREAMBLE                                                          \
    __shared__ __attribute__((aligned(16))) unsigned short As[2][128 * 32];    \
    __shared__ __attribute__((aligned(16))) unsigned short Bs[2][128 * 32];    \
    const int tid  = threadIdx.x;                                              \
    const int lane = tid & 63;                                                 \
    const int w    = tid >> 6;          /* 0..7 */                             \
    const int wr   = w >> 1, wc = w & 1; /* 4x2 wave grid */                   \
    const int lm   = lane & 15, quad = lane >> 4;                              \
    const int m0   = blockIdx.x * 128, n0 = blockIdx.y * 128;                  \
    f32x4 acc[2][4] = {};

template <int EPI, int OUT_BF16, int NGUARD>
__global__ __launch_bounds__(512, 6)
void gemm_mfma(const unsigned short* __restrict__ A,
               const unsigned short* __restrict__ Bt,
               const float* __restrict__ bias,
               void* __restrict__ Cv, int ldc, int Nreal, int K)
{
    GEMM_PREAMBLE
    GEMM_CORE(A, Bt, K)
    #pragma unroll
    for (int mi = 0; mi < 2; ++mi)
        #pragma unroll
        for (int r = 0; r < 4; ++r) {
            const size_t row = m0 + wr * 32 + mi * 16 + quad * 4 + r;
            #pragma unroll
            for (int ni = 0; ni < 4; ++ni) {
                const int col = n0 + wc * 64 + ni * 16 + lm;
                if (!NGUARD || col < Nreal) {
                    float v = acc[mi][ni][r] + bias[col];
                    if (EPI == EPI_RELU) v = fmaxf(v, 0.f);
                    if (EPI == EPI_TANH) v = tanhfast(v);
                    if (OUT_BF16) ((unsigned short*)Cv)[row * ldc + col] = f2bf(v);
                    else          ((float*)Cv)[row * ldc + col] = v;
                }
            }
        }
}

// ---- LSTM weight pack (enc+dec in one launch; blockIdx.y selects) ----
// kk-major, lane-major fragment layout:
//   elem(np, k) -> kk*49152 + (w*12+ni)*512 + (quad*16+lm)*8 + j   (shorts)
// where np = w*192+ni*16+lm, k = kk*32+quad*8+j. Kp=448 both (dec k>=401
// zero-padded).
struct PackArgs {
    const float *Wa0, *Wb0, *bias0; unsigned short* Wt0; float* bI0; int K10, K0, Kp0;
    const float *Wa1, *Wb1, *bias1; unsigned short* Wt1; float* bI1; int K11, K1, Kp1;
};
__global__ void pack_lstm2(PackArgs p)
{
    const float* Wa  = blockIdx.y ? p.Wa1  : p.Wa0;
    const float* Wb  = blockIdx.y ? p.Wb1  : p.Wb0;
    const float* bias= blockIdx.y ? p.bias1: p.bias0;
    unsigned short* Wt = blockIdx.y ? p.Wt1 : p.Wt0;
    float* biasI = blockIdx.y ? p.bI1 : p.bI0;
    const int K1 = blockIdx.y ? p.K11 : p.K10;
    const int K  = blockIdx.y ? p.K1  : p.K0;
    const int Kp = blockIdx.y ? p.Kp1 : p.Kp0;
    const int idx = blockIdx.x * 256 + threadIdx.x;
    if (idx >= 1536 * Kp) return;
    const int np = idx / Kp, k = idx - np * Kp;
    const int ub = np >> 6, g = (np >> 4) & 3, ul = np & 15;
    const int u = ub * 16 + ul;
    const bool valid = (u < 356);
    const int norig = g * 356 + u;
    float v = 0.f;
    if (valid && k < K)
        v = (k < K1) ? Wa[(size_t)k * 1424 + norig]
                     : Wb[(size_t)(k - K1) * 1424 + norig];
    // kk-major, lane-major fragment layout
    const int wv = np / 192, rem = np - wv * 192;
    const int ni = rem >> 4, lmv = rem & 15;
    const int kkv = k >> 5, kq = k & 31;
    const int qd = kq >> 3, j = kq & 7;
    Wt[(size_t)kkv * 49152 + (size_t)(wv * 12 + ni) * 512 + (qd * 16 + lmv) * 8 + j]
        = f2bf(v);
    if (k == 0) biasI[np] = valid ? bias[norig] : 0.f;
}

// ---- MLP weight transpose+pack (fp32 [K][N] -> bf16 [Np][Kp]) ----
__global__ void transpose_pack(const float* __restrict__ W, int K, int N,
                               unsigned short* __restrict__ Wt, int Kp, int Np)
{
    __shared__ float t[32][33];
    const int n0 = blockIdx.x * 32, k0 = blockIdx.y * 32;
    const int tx = threadIdx.x, ty = threadIdx.y;
    #pragma unroll
    for (int r = 0; r < 4; ++r) {
        const int k = k0 + ty + 8 * r, n = n0 + tx;
        t[ty + 8 * r][tx] = (k < K && n < N) ? W[(size_t)k * N + n] : 0.f;
    }
    __syncthreads();
    #pragma unroll
    for (int r = 0; r < 4; ++r) {
        const int k = k0 + tx, n = n0 + ty + 8 * r;
        if (k < Kp && n < Np) Wt[(size_t)n * Kp + k] = f2bf(t[tx][ty + 8 * r]);
    }
}

// three 1024x1024 transposes in one launch (blockIdx.z selects)
struct WP3 { const float *s0, *s1, *s2; unsigned short *d0, *d1, *d2; };
__global__ void transpose_pack3(WP3 p)
{
    __shared__ float t[32][33];
    const float* W = (blockIdx.z == 0) ? p.s0 : (blockIdx.z == 1) ? p.s1 : p.s2;
    unsigned short* Wt = (blockIdx.z == 0) ? p.d0 : (blockIdx.z == 1) ? p.d1 : p.d2;
    const int n0 = blockIdx.x * 32, k0 = blockIdx.y * 32;
    const int tx = threadIdx.x, ty = threadIdx.y;
    #pragma unroll
    for (int r = 0; r < 4; ++r)
        t[ty + 8 * r][tx] = W[(size_t)(k0 + ty + 8 * r) * 1024 + n0 + tx];
    __syncthreads();
    #pragma unroll
    for (int r = 0; r < 4; ++r)
        Wt[(size_t)(n0 + ty + 8 * r) * 1024 + k0 + tx] = f2bf(t[tx][ty + 8 * r]);
}

// ---- zero dcd pad cols (2492..2495 of each row) ----
__global__ void zero_dcd_pad(unsigned short* __restrict__ dcd)
{
    const int i = blockIdx.x * 256 + threadIdx.x;
    if (i < 8192 * 4) dcd[(size_t)(i >> 2) * 2496 + 2492 + (i & 3)] = 0;
}

extern "C" void kernel_launch(void* const* d_in, const int* in_sizes, int n_in,
                              void* d_out, int out_size, void* d_ws, size_t ws_size,
                              hipStream_t stream)
{
    const float* x     = (const float*)d_in[0];
    const float* m     = (const float*)d_in[1];
    const float* enc_W = (const float*)d_in[2];
    const float* enc_U = (const float*)d_in[3];
    const float* enc_b = (const float*)d_in[4];
    const float* dec_W = (const float*)d_in[5];
    const float* dec_Um= (const float*)d_in[6];
    const float* dec_b = (const float*)d_in[7];
    const float* W_map = (const float*)d_in[8];
    const float* b_map = (const float*)d_in[9];
    const float* W1    = (const float*)d_in[10];
    const float* b1    = (const float*)d_in[11];
    const float* W2    = (const float*)d_in[12];
    const float* b2    = (const float*)d_in[13];
    const float* W3    = (const float*)d_in[14];
    const float* b3    = (const float*)d_in[15];
    const float* W_out = (const float*)d_in[16];
    const float* b_out = (const float*)d_in[17];
    float* out = (float*)d_out;

    const int B = 8192, FE = 69, FD = 45;
    const int KMP = 2496;

    char* ws = (char*)d_ws;
    size_t off = 0;
    auto alloc = [&](size_t bytes) -> void* {
        void* p = ws + off; off = (off + bytes + 255) & ~(size_t)255; return p;
    };
    unsigned short* WtE = (unsigned short*)alloc((size_t)1536 * 448 * 2);
    unsigned short* WtD = (unsigned short*)alloc((size_t)1536 * 448 * 2);
    unsigned short* WtM = (unsigned short*)alloc((size_t)1024 * KMP * 2);
    unsigned short* Wt1 = (unsigned short*)alloc((size_t)1024 * 1024 * 2);
    unsigned short* Wt2 = (unsigned short*)alloc((size_t)1024 * 1024 * 2);
    unsigned short* Wt3 = (unsigned short*)alloc((size_t)1024 * 1024 * 2);
    unsigned short* WtO = (unsigned short*)alloc((size_t)256 * 1024 * 2);
    float* bIE = (float*)alloc(1536 * 4);
    float* bID = (float*)alloc(1536 * 4);
    unsigned short* dcd = (unsigned short*)alloc((size_t)B * KMP * 2);
    unsigned short* a1  = (unsigned short*)alloc((size_t)B * 1024 * 2);
    unsigned short* a2  = (unsigned short*)alloc((size_t)B * 1024 * 2);

    // ---- weight packing (Kp=448 both, kk-major lane-major frags) ----
    PackArgs pa{enc_W, enc_U, enc_b, WtE, bIE, FE, FE + 356, 448,
                dec_W, dec_Um, dec_b, WtD, bID, FD, FD + 356, 448};
    pack_lstm2<<<dim3((1536 * 448 + 255) / 256, 2), 256, 0, stream>>>(pa);
    const dim3 tb(32, 8);
    transpose_pack<<<dim3(1024 / 32, KMP / 32), tb, 0, stream>>>(
        W_map, 2492, 1024, WtM, KMP, 1024);
    WP3 p3{W1, W2, W3, Wt1, Wt2, Wt3};
    transpose_pack3<<<dim3(32, 32, 3), tb, 0, stream>>>(p3);
    transpose_pack<<<dim3(256 / 32, 1024 / 32), tb, 0, stream>>>(
        W_out, 1024, 168, WtO, 1024, 256);
    zero_dcd_pad<<<(8192 * 4 + 255) / 256, 256, 0, stream>>>(dcd);

    // ---- persistent LSTM: one plain launch, zero grid sync ----
    lstm_persist<<<256, 512, 0, stream>>>(x, m, WtE, WtD, bIE, bID, dcd);

    // ---- MLP head ----
    gemm_mfma<EPI_RELU, 1, 0><<<dim3(64, 8), 512, 0, stream>>>(
        dcd, WtM, b_map, a1, 1024, 1024, KMP);
    gemm_mfma<EPI_TANH, 1, 0><<<dim3(64, 8), 512, 0, stream>>>(
        a1, Wt1, b1, a2, 1024, 1024, 1024);
    gemm_mfma<EPI_TANH, 1, 0><<<dim3(64, 8), 512, 0, stream>>>(
        a2, Wt2, b2, a1, 1024, 1024, 1024);
    gemm_mfma<EPI_TANH, 1, 0><<<dim3(64, 8), 512, 0, stream>>>(
        a1, Wt3, b3, a2, 1024, 1024, 1024);
    gemm_mfma<EPI_NONE, 0, 1><<<dim3(64, 2), 512, 0, stream>>>(
        a2, WtO, b_out, out, 168, 168, 1024);
}

// Round 12
// 565.811 us; speedup vs baseline: 1.6894x; 1.0078x over previous
//
#include <hip/hip_runtime.h>
#include <math.h>

// ---------------------------------------------------------------------------
// Round 21: remove the LDS round-trip for B — direct global->VGPR fragment
// loads on r20's proven counted-vmcnt schedule. r20 post-mortem: chain 344us
// (best), but per kk per CU the weights cost 96KB LDS write (DMA) + 96KB
// LDS read (~12cyc/ds_read_b128 on the shared port ~ 7us/step) for data each
// wave uses ONCE; gll16 address math kept VALUBusy at 50%. Now: B fragment
// = global_load_dwordx4 at SGPR base + uniform lane*16B voffset (addr math
// -> scalar pipe), 3 rotating 4-frag register buffers (48 VGPR), SAME
// schedule as r20 (issue chunk c+2, vmcnt(8), 8 MFMAs; tail 8/4/0). LDS
// shrinks to Ab only (29KB). waves_per_eu(2,2) gives the 256-VGPR budget
// (r15's 128-cap failure mode); VGPR ~210 pins 1 block/CU. Telltales:
// VGPR_Count ~190-240, LDS_Block_Size 29184.
// ---------------------------------------------------------------------------

using bf16x8 = __attribute__((ext_vector_type(8))) short;
using f32x4  = __attribute__((ext_vector_type(4))) float;

enum { EPI_NONE = 0, EPI_RELU = 1, EPI_TANH = 2 };

__device__ inline unsigned short f2bf(float f) {
    union { float f; unsigned u; } v; v.f = f;
    unsigned r = v.u + 0x7FFFu + ((v.u >> 16) & 1u);
    return (unsigned short)(r >> 16);
}
__device__ inline float sigf(float x) {
    return __fdividef(1.f, 1.f + __expf(-x));
}
__device__ inline float tanhfast(float x) {
    return 1.f - __fdividef(2.f, 1.f + __expf(2.f * x));
}

__device__ inline void gll16(const void* g, void* l) {
    __builtin_amdgcn_global_load_lds(
        (const __attribute__((address_space(1))) unsigned int*)(uintptr_t)g,
        (__attribute__((address_space(3))) unsigned int*)(unsigned int)(uintptr_t)l,
        16, 0, 0);
}

// ---------------------------------------------------------------------------
// Persistent LSTM: grid 256 x 512 threads, 1 block/CU (VGPR-pinned).
// Block b owns batch rows [32b, 32b+32). Ab [32][456] bf16 holds x|h.
// Wave w owns packed gate cols [192w,192w+192) = units {48w..48w+47}.
// Weight layout (pack_lstm2): elem(np = w*192+ni*16+lm, k = kk*32+quad*8+j)
// at kk*49152 + (w*12+ni)*512 + (quad*16+lm)*8 + j -> fragment (kk,ni) is
// 1KB contiguous; load = global_load_dwordx4 at base + lane*16B.
// ---------------------------------------------------------------------------
#define PROWS 32
#define PLDA  456

// load the 4 fragments of chunk (kkv, partv) directly into registers
#define LOADB_G(dst, kkv, partv)                                               \
    _Pragma("unroll")                                                          \
    for (int q = 0; q < 4; ++q)                                                \
        dst[q] = *(const bf16x8*)(Wt + (size_t)(kkv) * 49152                   \
                                  + (w * 12 + (partv) * 4 + q) * 512           \
                                  + lane * 8);

// load the 2 A-fragments for K-slice kkv from Ab
#define LOADA(dst, kkv)                                                        \
    _Pragma("unroll")                                                          \
    for (int mi = 0; mi < 2; ++mi)                                             \
        dst[mi] = *(const bf16x8*)&Ab[(mi * 16 + lm) * PLDA + (kkv) * 32       \
                                      + quad * 8];

// 8 MFMAs for part partv (LITERAL 0/1/2 -> static acc indices)
#define MFMA8(partv, bRv)                                                      \
    _Pragma("unroll")                                                          \
    for (int q = 0; q < 4; ++q) {                                              \
        acc[0][(partv) * 4 + q] = __builtin_amdgcn_mfma_f32_16x16x32_bf16(     \
            aF[0], bRv[q], acc[0][(partv) * 4 + q], 0, 0, 0);                  \
        acc[1][(partv) * 4 + q] = __builtin_amdgcn_mfma_f32_16x16x32_bf16(     \
            aF[1], bRv[q], acc[1][(partv) * 4 + q], 0, 0, 0);                  \
    }

#define VMWAIT(n)                                                              \
    asm volatile("s_waitcnt vmcnt(" #n ")" ::: "memory");                      \
    __builtin_amdgcn_sched_barrier(0);

__global__ __attribute__((amdgpu_flat_work_group_size(512, 512),
                          amdgpu_waves_per_eu(2, 2)))
void lstm_persist(const float* __restrict__ x,
                  const float* __restrict__ m,
                  const unsigned short* __restrict__ WtE,
                  const unsigned short* __restrict__ WtD,
                  const float* __restrict__ bIE,
                  const float* __restrict__ bID,
                  unsigned short* __restrict__ dcd)
{
    __shared__ __attribute__((aligned(16))) unsigned short Ab[PROWS * PLDA];
    const int tid  = threadIdx.x;
    const int lane = tid & 63;
    const int w    = tid >> 6;           // 0..7
    const int lm   = lane & 15, quad = lane >> 4;
    const int brow = blockIdx.x * PROWS;
    const int kk0  = blockIdx.x % 14;    // per-block kk stagger (L2 spread)

    // zero A-buffer (pads stay 0 forever), then stage x slice t=0
    for (int i = tid; i < PROWS * PLDA; i += 512) Ab[i] = 0;
    __syncthreads();
    for (int i = tid; i < PROWS * 69; i += 512) {
        const int r = i / 69, f = i - r * 69;
        Ab[r * PLDA + f] = f2bf(x[((size_t)(brow + r) * 7 + 0) * 69 + f]);
    }

    float creg[2][3][4] = {};   // cell state: [mi][a][r] for unit (3w+a)*16+lm
    float bI[3][4];             // bias: [a][gate]

    for (int s = 0; s < 14; ++s) {
        const bool enc = (s < 7);
        const int t = enc ? s : s - 7;
        const unsigned short* Wt = enc ? WtE : WtD;

        if (s == 0 || s == 7) {
            const float* bsrc = enc ? bIE : bID;
            #pragma unroll
            for (int a = 0; a < 3; ++a)
                #pragma unroll
                for (int g = 0; g < 4; ++g)
                    bI[a][g] = bsrc[(3 * w + a) * 64 + g * 16 + lm];
        }

        __syncthreads();   // Ab (x for s, h from s-1) visible; vmcnt drained

        f32x4 acc[2][12] = {};
        {
            bf16x8 b0[4], b1[4], b2[4];
            // prologue: chunks 0,1 of kk0 (8 loads outstanding)
            LOADB_G(b0, kk0, 0)
            LOADB_G(b1, kk0, 1)
            int kkc = kk0;
            #pragma unroll 1
            for (int i = 0; i < 14; ++i) {
                const int kkn = (kkc == 13) ? 0 : kkc + 1;
                bf16x8 aF[2];
                // part 0: issue (kkc,2); wait chunk(i,0); compute b0
                LOADB_G(b2, kkc, 2)
                VMWAIT(8)
                LOADA(aF, kkc)
                MFMA8(0, b0)
                // part 1: issue (kkn,0); wait chunk(i,1); compute b1
                if (i < 13) {
                    LOADB_G(b0, kkn, 0)
                    VMWAIT(8)
                } else {
                    VMWAIT(4)
                }
                MFMA8(1, b1)
                // part 2: issue (kkn,1); wait chunk(i,2); compute b2
                if (i < 13) {
                    LOADB_G(b1, kkn, 1)
                    VMWAIT(8)
                } else {
                    VMWAIT(0)
                }
                MFMA8(2, b2)
                kkc = kkn;
            }
        }

        __syncthreads();   // all Ab reads done before h overwrite

        // epilogue: gates -> c (regs) -> h -> Ab[hoff+u] (+ dcd in dec phase)
        const int hoff = (s < 6) ? 69 : 45;   // layout of step s+1
        #pragma unroll
        for (int mi = 0; mi < 2; ++mi)
            #pragma unroll
            for (int a = 0; a < 3; ++a) {
                const int u = (3 * w + a) * 16 + lm;
                const bool uok = (u < 356);
                #pragma unroll
                for (int r = 0; r < 4; ++r) {
                    const float zi = acc[mi][a * 4 + 0][r] + bI[a][0];
                    const float zf = acc[mi][a * 4 + 1][r] + bI[a][1];
                    const float zg = acc[mi][a * 4 + 2][r] + bI[a][2];
                    const float zo = acc[mi][a * 4 + 3][r] + bI[a][3];
                    const float cn = sigf(zf) * creg[mi][a][r]
                                   + sigf(zi) * tanhfast(zg);
                    creg[mi][a][r] = cn;
                    const unsigned short hb = f2bf(sigf(zo) * tanhfast(cn));
                    const int rl = mi * 16 + quad * 4 + r;
                    if (uok) {
                        if (s < 13) Ab[rl * PLDA + hoff + u] = hb;
                        if (!enc)
                            dcd[(size_t)(brow + rl) * 2496 + t * 356 + u] = hb;
                    }
                }
            }

        // stage x/m slice for step s+1 (disjoint from h region)
        const int sn = s + 1;
        if (sn < 7) {
            for (int i = tid; i < PROWS * 69; i += 512) {
                const int r = i / 69, f = i - r * 69;
                Ab[r * PLDA + f] =
                    f2bf(x[((size_t)(brow + r) * 7 + sn) * 69 + f]);
            }
        } else if (sn < 14) {
            for (int i = tid; i < PROWS * 45; i += 512) {
                const int r = i / 45, f = i - r * 45;
                Ab[r * PLDA + f] =
                    f2bf(m[((size_t)(brow + r) * 7 + (sn - 7)) * 45 + f]);
            }
        }
    }
}

// ---- MLP GEMM machinery (unchanged, proven) ----

#define STAGE(A_, Bt_, K_, k0_, b_)                                            \
    {                                                                          \
        const int row = tid >> 2, kc = tid & 3;                                \
        gll16((A_)  + (size_t)(m0 + row) * (K_) + (k0_) + kc * 8,              \
              (void*)&As[b_][tid * 8]);                                        \
        gll16((Bt_) + (size_t)(n0 + row) * (K_) + (k0_) + kc * 8,              \
              (void*)&Bs[b_][tid * 8]);                                        \
    }

#define GEMM_CORE(A_, Bt_, K_)                                                 \
    STAGE(A_, Bt_, K_, 0, 0)                                                   \
    {                                                                          \
        const int niter = (K_) / 32;                                           \
        for (int it = 0; it < niter; ++it) {                                   \
            __syncthreads();                                                   \
            if (it + 1 < niter) {                                              \
                const int kn = (it + 1) * 32, bn = (it + 1) & 1;               \
                STAGE(A_, Bt_, K_, kn, bn)                                     \
            }                                                                  \
            const unsigned short* Asb = As[it & 1];                            \
            const unsigned short* Bsb = Bs[it & 1];                            \
            bf16x8 aF[2], bF[4];                                               \
            _Pragma("unroll")                                                  \
            for (int mi = 0; mi < 2; ++mi)                                     \
                aF[mi] = *(const bf16x8*)(Asb + (wr*32 + mi*16 + lm)*32 + quad*8);\
            _Pragma("unroll")                                                  \
            for (int ni = 0; ni < 4; ++ni)                                     \
                bF[ni] = *(const bf16x8*)(Bsb + (wc*64 + ni*16 + lm)*32 + quad*8);\
            _Pragma("unroll")                                                  \
            for (int mi = 0; mi < 2; ++mi)                                     \
                _Pragma("unroll")                                              \
                for (int ni = 0; ni < 4; ++ni)                                 \
                    acc[mi][ni] = __builtin_amdgcn_mfma_f32_16x16x32_bf16(     \
                        aF[mi], bF[ni], acc[mi][ni], 0, 0, 0);                 \
        }                                                                      \
    }

#define GEMM_PREAMBLE                                                          \
    __shared__ __attribute__((aligned(16))) unsigned short As[2][128 * 32];    \
    __shared__ __attribute__((aligned(16))) unsigned short Bs[2][128 * 32];    \
    const int tid  = threadIdx.x;                                              \
    const int lane = tid & 63;                                                 \
    const int w    = tid >> 6;          /* 0..7 */                             \
    const int wr   = w >> 1, wc = w & 1; /* 4x2 wave grid */                   \
    const int lm   = lane & 15, quad = lane >> 4;                              \
    const int m0   = blockIdx.x * 128, n0 = blockIdx.y * 128;                  \
    f32x4 acc[2][4] = {};

template <int EPI, int OUT_BF16, int NGUARD>
__global__ __launch_bounds__(512, 6)
void gemm_mfma(const unsigned short* __restrict__ A,
               const unsigned short* __restrict__ Bt,
               const float* __restrict__ bias,
               void* __restrict__ Cv, int ldc, int Nreal, int K)
{
    GEMM_PREAMBLE
    GEMM_CORE(A, Bt, K)
    #pragma unroll
    for (int mi = 0; mi < 2; ++mi)
        #pragma unroll
        for (int r = 0; r < 4; ++r) {
            const size_t row = m0 + wr * 32 + mi * 16 + quad * 4 + r;
            #pragma unroll
            for (int ni = 0; ni < 4; ++ni) {
                const int col = n0 + wc * 64 + ni * 16 + lm;
                if (!NGUARD || col < Nreal) {
                    float v = acc[mi][ni][r] + bias[col];
                    if (EPI == EPI_RELU) v = fmaxf(v, 0.f);
                    if (EPI == EPI_TANH) v = tanhfast(v);
                    if (OUT_BF16) ((unsigned short*)Cv)[row * ldc + col] = f2bf(v);
                    else          ((float*)Cv)[row * ldc + col] = v;
                }
            }
        }
}

// ---- LSTM weight pack (enc+dec in one launch; blockIdx.y selects) ----
// kk-major, lane-major fragment layout:
//   elem(np, k) -> kk*49152 + (w*12+ni)*512 + (quad*16+lm)*8 + j   (shorts)
// where np = w*192+ni*16+lm, k = kk*32+quad*8+j. Kp=448 both (dec k>=401
// zero-padded).
struct PackArgs {
    const float *Wa0, *Wb0, *bias0; unsigned short* Wt0; float* bI0; int K10, K0, Kp0;
    const float *Wa1, *Wb1, *bias1; unsigned short* Wt1; float* bI1; int K11, K1, Kp1;
};
__global__ void pack_lstm2(PackArgs p)
{
    const float* Wa  = blockIdx.y ? p.Wa1  : p.Wa0;
    const float* Wb  = blockIdx.y ? p.Wb1  : p.Wb0;
    const float* bias= blockIdx.y ? p.bias1: p.bias0;
    unsigned short* Wt = blockIdx.y ? p.Wt1 : p.Wt0;
    float* biasI = blockIdx.y ? p.bI1 : p.bI0;
    const int K1 = blockIdx.y ? p.K11 : p.K10;
    const int K  = blockIdx.y ? p.K1  : p.K0;
    const int Kp = blockIdx.y ? p.Kp1 : p.Kp0;
    const int idx = blockIdx.x * 256 + threadIdx.x;
    if (idx >= 1536 * Kp) return;
    const int np = idx / Kp, k = idx - np * Kp;
    const int ub = np >> 6, g = (np >> 4) & 3, ul = np & 15;
    const int u = ub * 16 + ul;
    const bool valid = (u < 356);
    const int norig = g * 356 + u;
    float v = 0.f;
    if (valid && k < K)
        v = (k < K1) ? Wa[(size_t)k * 1424 + norig]
                     : Wb[(size_t)(k - K1) * 1424 + norig];
    // kk-major, lane-major fragment layout
    const int wv = np / 192, rem = np - wv * 192;
    const int ni = rem >> 4, lmv = rem & 15;
    const int kkv = k >> 5, kq = k & 31;
    const int qd = kq >> 3, j = kq & 7;
    Wt[(size_t)kkv * 49152 + (size_t)(wv * 12 + ni) * 512 + (qd * 16 + lmv) * 8 + j]
        = f2bf(v);
    if (k == 0) biasI[np] = valid ? bias[norig] : 0.f;
}

// ---- MLP weight transpose+pack (fp32 [K][N] -> bf16 [Np][Kp]) ----
__global__ void transpose_pack(const float* __restrict__ W, int K, int N,
                               unsigned short* __restrict__ Wt, int Kp, int Np)
{
    __shared__ float t[32][33];
    const int n0 = blockIdx.x * 32, k0 = blockIdx.y * 32;
    const int tx = threadIdx.x, ty = threadIdx.y;
    #pragma unroll
    for (int r = 0; r < 4; ++r) {
        const int k = k0 + ty + 8 * r, n = n0 + tx;
        t[ty + 8 * r][tx] = (k < K && n < N) ? W[(size_t)k * N + n] : 0.f;
    }
    __syncthreads();
    #pragma unroll
    for (int r = 0; r < 4; ++r) {
        const int k = k0 + tx, n = n0 + ty + 8 * r;
        if (k < Kp && n < Np) Wt[(size_t)n * Kp + k] = f2bf(t[tx][ty + 8 * r]);
    }
}

// three 1024x1024 transposes in one launch (blockIdx.z selects)
struct WP3 { const float *s0, *s1, *s2; unsigned short *d0, *d1, *d2; };
__global__ void transpose_pack3(WP3 p)
{
    __shared__ float t[32][33];
    const float* W = (blockIdx.z == 0) ? p.s0 : (blockIdx.z == 1) ? p.s1 : p.s2;
    unsigned short* Wt = (blockIdx.z == 0) ? p.d0 : (blockIdx.z == 1) ? p.d1 : p.d2;
    const int n0 = blockIdx.x * 32, k0 = blockIdx.y * 32;
    const int tx = threadIdx.x, ty = threadIdx.y;
    #pragma unroll
    for (int r = 0; r < 4; ++r)
        t[ty + 8 * r][tx] = W[(size_t)(k0 + ty + 8 * r) * 1024 + n0 + tx];
    __syncthreads();
    #pragma unroll
    for (int r = 0; r < 4; ++r)
        Wt[(size_t)(n0 + ty + 8 * r) * 1024 + k0 + tx] = f2bf(t[tx][ty + 8 * r]);
}

// ---- zero dcd pad cols (2492..2495 of each row) ----
__global__ void zero_dcd_pad(unsigned short* __restrict__ dcd)
{
    const int i = blockIdx.x * 256 + threadIdx.x;
    if (i < 8192 * 4) dcd[(size_t)(i >> 2) * 2496 + 2492 + (i & 3)] = 0;
}

extern "C" void kernel_launch(void* const* d_in, const int* in_sizes, int n_in,
                              void* d_out, int out_size, void* d_ws, size_t ws_size,
                              hipStream_t stream)
{
    const float* x     = (const float*)d_in[0];
    const float* m     = (const float*)d_in[1];
    const float* enc_W = (const float*)d_in[2];
    const float* enc_U = (const float*)d_in[3];
    const float* enc_b = (const float*)d_in[4];
    const float* dec_W = (const float*)d_in[5];
    const float* dec_Um= (const float*)d_in[6];
    const float* dec_b = (const float*)d_in[7];
    const float* W_map = (const float*)d_in[8];
    const float* b_map = (const float*)d_in[9];
    const float* W1    = (const float*)d_in[10];
    const float* b1    = (const float*)d_in[11];
    const float* W2    = (const float*)d_in[12];
    const float* b2    = (const float*)d_in[13];
    const float* W3    = (const float*)d_in[14];
    const float* b3    = (const float*)d_in[15];
    const float* W_out = (const float*)d_in[16];
    const float* b_out = (const float*)d_in[17];
    float* out = (float*)d_out;

    const int B = 8192, FE = 69, FD = 45;
    const int KMP = 2496;

    char* ws = (char*)d_ws;
    size_t off = 0;
    auto alloc = [&](size_t bytes) -> void* {
        void* p = ws + off; off = (off + bytes + 255) & ~(size_t)255; return p;
    };
    unsigned short* WtE = (unsigned short*)alloc((size_t)1536 * 448 * 2);
    unsigned short* WtD = (unsigned short*)alloc((size_t)1536 * 448 * 2);
    unsigned short* WtM = (unsigned short*)alloc((size_t)1024 * KMP * 2);
    unsigned short* Wt1 = (unsigned short*)alloc((size_t)1024 * 1024 * 2);
    unsigned short* Wt2 = (unsigned short*)alloc((size_t)1024 * 1024 * 2);
    unsigned short* Wt3 = (unsigned short*)alloc((size_t)1024 * 1024 * 2);
    unsigned short* WtO = (unsigned short*)alloc((size_t)256 * 1024 * 2);
    float* bIE = (float*)alloc(1536 * 4);
    float* bID = (float*)alloc(1536 * 4);
    unsigned short* dcd = (unsigned short*)alloc((size_t)B * KMP * 2);
    unsigned short* a1  = (unsigned short*)alloc((size_t)B * 1024 * 2);
    unsigned short* a2  = (unsigned short*)alloc((size_t)B * 1024 * 2);

    // ---- weight packing (Kp=448 both, kk-major lane-major frags) ----
    PackArgs pa{enc_W, enc_U, enc_b, WtE, bIE, FE, FE + 356, 448,
                dec_W, dec_Um, dec_b, WtD, bID, FD, FD + 356, 448};
    pack_lstm2<<<dim3((1536 * 448 + 255) / 256, 2), 256, 0, stream>>>(pa);
    const dim3 tb(32, 8);
    transpose_pack<<<dim3(1024 / 32, KMP / 32), tb, 0, stream>>>(
        W_map, 2492, 1024, WtM, KMP, 1024);
    WP3 p3{W1, W2, W3, Wt1, Wt2, Wt3};
    transpose_pack3<<<dim3(32, 32, 3), tb, 0, stream>>>(p3);
    transpose_pack<<<dim3(256 / 32, 1024 / 32), tb, 0, stream>>>(
        W_out, 1024, 168, WtO, 1024, 256);
    zero_dcd_pad<<<(8192 * 4 + 255) / 256, 256, 0, stream>>>(dcd);

    // ---- persistent LSTM: one plain launch, zero grid sync ----
    lstm_persist<<<256, 512, 0, stream>>>(x, m, WtE, WtD, bIE, bID, dcd);

    // ---- MLP head ----
    gemm_mfma<EPI_RELU, 1, 0><<<dim3(64, 8), 512, 0, stream>>>(
        dcd, WtM, b_map, a1, 1024, 1024, KMP);
    gemm_mfma<EPI_TANH, 1, 0><<<dim3(64, 8), 512, 0, stream>>>(
        a1, Wt1, b1, a2, 1024, 1024, 1024);
    gemm_mfma<EPI_TANH, 1, 0><<<dim3(64, 8), 512, 0, stream>>>(
        a2, Wt2, b2, a1, 1024, 1024, 1024);
    gemm_mfma<EPI_TANH, 1, 0><<<dim3(64, 8), 512, 0, stream>>>(
        a1, Wt3, b3, a2, 1024, 1024, 1024);
    gemm_mfma<EPI_NONE, 0, 1><<<dim3(64, 2), 512, 0, stream>>>(
        a2, WtO, b_out, out, 168, 168, 1024);
}